// Round 1
// baseline (1999.162 us; speedup 1.0000x reference)
//
#include <hip/hip_runtime.h>
#include <math.h>

#define BB 2
#define LL 2048
#define DM 1024
#define DS 16
#define DI 2048
#define KX 33          // 1 + 2*D_STATE
#define D2 (2*DI)      // 4096

// ---------------------------------------------------------------------------
// GEMM1: xz[b][d][l] = sum_m W_in[d][m] * hs[b][l][m]
// A = W_in (4096 x 1024, K contiguous), B = hs ((b*L) x 1024, K contiguous)
// C = A * B^T, tiled 64x64x32, 256 threads, 4x4 microtile.
// ---------------------------------------------------------------------------
__global__ __launch_bounds__(256) void gemm1_k(const float* __restrict__ hs,
                                               const float* __restrict__ Win,
                                               float* __restrict__ xz) {
    __shared__ float As[32][68];  // [k][d]
    __shared__ float Bs[32][68];  // [k][bl]
    const int bn = blockIdx.x;    // bl tile (64 tiles)
    const int bm = blockIdx.y;    // d tile  (64 tiles)
    const int tid = threadIdx.x;
    const int tx = tid & 15, ty = tid >> 4;
    const int d0 = bm * 64, bl0 = bn * 64;
    const int b = bl0 >> 11, l0 = bl0 & (LL - 1);

    float acc[4][4] = {};
    for (int k0 = 0; k0 < DM; k0 += 32) {
        #pragma unroll
        for (int i = 0; i < 2; i++) {
            int idx = tid + i * 256;          // 0..511
            int row = idx >> 3;               // 0..63
            int c4  = (idx & 7) * 4;          // 0..28
            float4 va = *(const float4*)&Win[(size_t)(d0 + row) * DM + k0 + c4];
            As[c4 + 0][row] = va.x; As[c4 + 1][row] = va.y;
            As[c4 + 2][row] = va.z; As[c4 + 3][row] = va.w;
            float4 vb = *(const float4*)&hs[(size_t)(bl0 + row) * DM + k0 + c4];
            Bs[c4 + 0][row] = vb.x; Bs[c4 + 1][row] = vb.y;
            Bs[c4 + 2][row] = vb.z; Bs[c4 + 3][row] = vb.w;
        }
        __syncthreads();
        #pragma unroll
        for (int k = 0; k < 32; k++) {
            float4 av = *(const float4*)&As[k][ty * 4];
            float4 bv = *(const float4*)&Bs[k][tx * 4];
            float a[4] = {av.x, av.y, av.z, av.w};
            float c[4] = {bv.x, bv.y, bv.z, bv.w};
            #pragma unroll
            for (int i = 0; i < 4; i++)
                #pragma unroll
                for (int j = 0; j < 4; j++)
                    acc[i][j] = fmaf(a[i], c[j], acc[i][j]);
        }
        __syncthreads();
    }
    #pragma unroll
    for (int i = 0; i < 4; i++) {
        float4 v = {acc[i][0], acc[i][1], acc[i][2], acc[i][3]};
        *(float4*)&xz[((size_t)b * D2 + d0 + ty * 4 + i) * LL + l0 + tx * 4] = v;
    }
}

// ---------------------------------------------------------------------------
// Depthwise causal conv(4) + bias + SiLU on x-half of xz -> xc
// ---------------------------------------------------------------------------
__global__ __launch_bounds__(256) void conv_silu_k(const float* __restrict__ xz,
                                                   const float* __restrict__ cw,
                                                   const float* __restrict__ cb,
                                                   float* __restrict__ xc) {
    const int row = blockIdx.x;             // 0..B*DI-1
    const int b = row / DI, d = row % DI;
    const float* xr = xz + ((size_t)b * D2 + d) * LL;
    float w0 = cw[d * 4 + 0], w1 = cw[d * 4 + 1];
    float w2 = cw[d * 4 + 2], w3 = cw[d * 4 + 3];
    float bias = cb[d];
    const int l0 = threadIdx.x * 8;
    float buf[11];
    #pragma unroll
    for (int i = 0; i < 11; i++) {
        int l = l0 - 3 + i;
        buf[i] = (l >= 0) ? xr[l] : 0.f;
    }
    float* out = xc + ((size_t)b * DI + d) * LL;
    #pragma unroll
    for (int j = 0; j < 8; j++) {
        float s = fmaf(buf[j], w0, fmaf(buf[j + 1], w1,
                  fmaf(buf[j + 2], w2, fmaf(buf[j + 3], w3, bias))));
        out[l0 + j] = s / (1.f + expf(-s));
    }
}

// ---------------------------------------------------------------------------
// x_dbl partials: part[seg][b][k][l] = sum_{d in seg} xc[b][d][l]*Wx[k][d]
// 8 d-segments of 256. Deterministic (no atomics).
// ---------------------------------------------------------------------------
__global__ __launch_bounds__(256) void xproj_partial_k(const float* __restrict__ xc,
                                                       const float* __restrict__ Wx,
                                                       float* __restrict__ part) {
    const int blk = blockIdx.x;            // b*64 + seg*8 + lt
    const int b = blk >> 6, seg = (blk >> 3) & 7, lt = blk & 7;
    const int l = lt * 256 + threadIdx.x;
    __shared__ float w[KX][64];
    float acc[KX] = {};
    const float* xb = xc + (size_t)b * DI * LL;
    for (int dc = 0; dc < 256; dc += 64) {
        const int dbase = seg * 256 + dc;
        __syncthreads();
        for (int i = threadIdx.x; i < KX * 64; i += 256) {
            int kk = i >> 6, dd = i & 63;
            w[kk][dd] = Wx[(size_t)kk * DI + dbase + dd];
        }
        __syncthreads();
        for (int dd = 0; dd < 64; dd++) {
            float v = xb[(size_t)(dbase + dd) * LL + l];
            #pragma unroll
            for (int kk = 0; kk < KX; kk++) acc[kk] = fmaf(v, w[kk][dd], acc[kk]);
        }
    }
    for (int kk = 0; kk < KX; kk++)
        part[(((size_t)seg * BB + b) * KX + kk) * LL + l] = acc[kk];
}

__global__ __launch_bounds__(256) void xproj_reduce_k(const float* __restrict__ part,
                                                      float* __restrict__ xdbl) {
    const int i = blockIdx.x * 256 + threadIdx.x;   // B*KX*L = 135168
    float s = 0.f;
    #pragma unroll
    for (int seg = 0; seg < 8; seg++) s += part[(size_t)seg * BB * KX * LL + i];
    xdbl[i] = s;
}

// ---------------------------------------------------------------------------
// Selective scan, fused with +x*D_skip and *silu(z). Thread = (d_local, n).
// 256 blocks (B x DI/16), 256 threads. h kept in a register. In-place into xc.
// ---------------------------------------------------------------------------
__global__ __launch_bounds__(256) void scan_k(float* __restrict__ xc,
                                              const float* __restrict__ xz,
                                              const float* __restrict__ xdbl,
                                              const float* __restrict__ Wdt,
                                              const float* __restrict__ bdt,
                                              const float* __restrict__ Alog,
                                              const float* __restrict__ Dskip) {
    const int blk = blockIdx.x;            // B * 128
    const int b = blk >> 7, d0 = (blk & 127) * 16;
    const int tid = threadIdx.x;
    const int dl = tid >> 4, n = tid & 15;
    const int d = d0 + dl;

    const float a = -expf(Alog[(size_t)d * DS + n]);
    const float wdt = Wdt[d], bv = bdt[d], dsk = Dskip[d];
    const float* db = xdbl + (size_t)b * KX * LL;

    __shared__ float sx[16][65], sz[16][65], sd[KX][65];
    float h = 0.f;

    for (int c0 = 0; c0 < LL; c0 += 64) {
        __syncthreads();
        {
            int r = tid >> 4, c = (tid & 15) * 4;
            float4 vx = *(const float4*)&xc[((size_t)b * DI + d0 + r) * LL + c0 + c];
            sx[r][c] = vx.x; sx[r][c + 1] = vx.y; sx[r][c + 2] = vx.z; sx[r][c + 3] = vx.w;
            float4 vz = *(const float4*)&xz[((size_t)b * D2 + DI + d0 + r) * LL + c0 + c];
            sz[r][c] = vz.x; sz[r][c + 1] = vz.y; sz[r][c + 2] = vz.z; sz[r][c + 3] = vz.w;
            for (int kk = r; kk < KX; kk += 16) {
                float4 vd = *(const float4*)&db[(size_t)kk * LL + c0 + c];
                sd[kk][c] = vd.x; sd[kk][c + 1] = vd.y; sd[kk][c + 2] = vd.z; sd[kk][c + 3] = vd.w;
            }
        }
        __syncthreads();
        for (int ll = 0; ll < 64; ll++) {
            float dtr = sd[0][ll];
            float dt = fmaf(wdt, dtr, bv);
            dt = fmaxf(dt, 0.f) + log1pf(expf(-fabsf(dt)));   // stable softplus
            float xv = sx[dl][ll];
            float Bn = sd[1 + n][ll], Cn = sd[17 + n][ll];
            float dA = expf(dt * a);
            h = fmaf(dA, h, dt * xv * Bn);
            float contrib = h * Cn;
            contrib += __shfl_xor(contrib, 1);
            contrib += __shfl_xor(contrib, 2);
            contrib += __shfl_xor(contrib, 4);
            contrib += __shfl_xor(contrib, 8);
            if (n == 0) {
                float zv = sz[dl][ll];
                float yv = contrib + xv * dsk;
                yv = yv * (zv / (1.f + expf(-zv)));
                xc[((size_t)b * DI + d) * LL + c0 + ll] = yv;   // in-place y
            }
        }
    }
}

// ---------------------------------------------------------------------------
// GEMM2: out[b][l][m] = sum_d y[b][d][l] * W_out[m][d]
// ---------------------------------------------------------------------------
__global__ __launch_bounds__(256) void gemm2_k(const float* __restrict__ y,
                                               const float* __restrict__ Wout,
                                               float* __restrict__ out) {
    __shared__ float Ys[32][68];  // [k][l]
    __shared__ float Ws[32][68];  // [k][m]
    const int bn = blockIdx.x;    // m tile (16)
    const int bm = blockIdx.y;    // bl tile (64)
    const int tid = threadIdx.x;
    const int tx = tid & 15, ty = tid >> 4;
    const int bl0 = bm * 64, m0 = bn * 64;
    const int b = bl0 >> 11, l0 = bl0 & (LL - 1);

    float acc[4][4] = {};
    for (int k0 = 0; k0 < DI; k0 += 32) {
        #pragma unroll
        for (int i = 0; i < 2; i++) {
            int idx = tid + i * 256;
            int kk = idx >> 4;                // 0..31
            int c4 = (idx & 15) * 4;          // 0..60
            float4 v = *(const float4*)&y[((size_t)b * DI + k0 + kk) * LL + l0 + c4];
            *(float4*)&Ys[kk][c4] = v;
            int row = idx >> 3;               // 0..63
            int k4 = (idx & 7) * 4;           // 0..28
            float4 w = *(const float4*)&Wout[(size_t)(m0 + row) * DI + k0 + k4];
            Ws[k4 + 0][row] = w.x; Ws[k4 + 1][row] = w.y;
            Ws[k4 + 2][row] = w.z; Ws[k4 + 3][row] = w.w;
        }
        __syncthreads();
        #pragma unroll
        for (int k = 0; k < 32; k++) {
            float4 av = *(const float4*)&Ys[k][ty * 4];
            float4 bw = *(const float4*)&Ws[k][tx * 4];
            float a[4] = {av.x, av.y, av.z, av.w};
            float c[4] = {bw.x, bw.y, bw.z, bw.w};
            #pragma unroll
            for (int i = 0; i < 4; i++)
                #pragma unroll
                for (int j = 0; j < 4; j++)
                    acc[i][j] = fmaf(a[i], c[j], acc[i][j]);
        }
        __syncthreads();
    }
    #pragma unroll
    for (int i = 0; i < 4; i++) {
        float4 v = {acc[i][0], acc[i][1], acc[i][2], acc[i][3]};
        *(float4*)&out[((size_t)b * LL + l0 + ty * 4 + i) * DM + m0 + tx * 4] = v;
    }
}

// ---------------------------------------------------------------------------
extern "C" void kernel_launch(void* const* d_in, const int* in_sizes, int n_in,
                              void* d_out, int out_size, void* d_ws, size_t ws_size,
                              hipStream_t stream) {
    const float* hs   = (const float*)d_in[0];
    const float* Win  = (const float*)d_in[1];
    const float* cw   = (const float*)d_in[2];
    const float* cb   = (const float*)d_in[3];
    const float* Wx   = (const float*)d_in[4];
    const float* Wdt  = (const float*)d_in[5];
    const float* bdt  = (const float*)d_in[6];
    const float* Alog = (const float*)d_in[7];
    const float* Dsk  = (const float*)d_in[8];
    const float* Wout = (const float*)d_in[9];
    float* out = (float*)d_out;

    float* xz   = (float*)d_ws;                            // B*4096*L
    float* xc   = xz   + (size_t)BB * D2 * LL;             // B*DI*L
    float* part = xc   + (size_t)BB * DI * LL;             // 8*B*KX*L
    float* xdbl = part + (size_t)8 * BB * KX * LL;         // B*KX*L

    gemm1_k<<<dim3(64, 64), 256, 0, stream>>>(hs, Win, xz);
    conv_silu_k<<<BB * DI, 256, 0, stream>>>(xz, cw, cb, xc);
    xproj_partial_k<<<128, 256, 0, stream>>>(xc, Wx, part);
    xproj_reduce_k<<<(BB * KX * LL) / 256, 256, 0, stream>>>(part, xdbl);
    scan_k<<<BB * (DI / 16), 256, 0, stream>>>(xc, xz, xdbl, Wdt, bdt, Alog, Dsk);
    gemm2_k<<<dim3(16, 64), 256, 0, stream>>>(xc, Wout, out);
}

// Round 2
// 1031.194 us; speedup vs baseline: 1.9387x; 1.9387x over previous
//
#include <hip/hip_runtime.h>
#include <math.h>

#define BB 2
#define LL 2048
#define DM 1024
#define DS 16
#define DI 2048
#define KX 33          // 1 + 2*D_STATE
#define D2 (2*DI)      // 4096
#define NC 16          // scan chunks
#define LC 128         // chunk length (NC*LC == LL)

// ---------------------------------------------------------------------------
// GEMM1: xz[b][d][l] = sum_m W_in[d][m] * hs[b][l][m]
// ---------------------------------------------------------------------------
__global__ __launch_bounds__(256) void gemm1_k(const float* __restrict__ hs,
                                               const float* __restrict__ Win,
                                               float* __restrict__ xz) {
    __shared__ float As[32][68];  // [k][d]
    __shared__ float Bs[32][68];  // [k][bl]
    const int bn = blockIdx.x;    // bl tile (64 tiles)
    const int bm = blockIdx.y;    // d tile  (64 tiles)
    const int tid = threadIdx.x;
    const int tx = tid & 15, ty = tid >> 4;
    const int d0 = bm * 64, bl0 = bn * 64;
    const int b = bl0 >> 11, l0 = bl0 & (LL - 1);

    float acc[4][4] = {};
    for (int k0 = 0; k0 < DM; k0 += 32) {
        #pragma unroll
        for (int i = 0; i < 2; i++) {
            int idx = tid + i * 256;          // 0..511
            int row = idx >> 3;               // 0..63
            int c4  = (idx & 7) * 4;          // 0..28
            float4 va = *(const float4*)&Win[(size_t)(d0 + row) * DM + k0 + c4];
            As[c4 + 0][row] = va.x; As[c4 + 1][row] = va.y;
            As[c4 + 2][row] = va.z; As[c4 + 3][row] = va.w;
            float4 vb = *(const float4*)&hs[(size_t)(bl0 + row) * DM + k0 + c4];
            Bs[c4 + 0][row] = vb.x; Bs[c4 + 1][row] = vb.y;
            Bs[c4 + 2][row] = vb.z; Bs[c4 + 3][row] = vb.w;
        }
        __syncthreads();
        #pragma unroll
        for (int k = 0; k < 32; k++) {
            float4 av = *(const float4*)&As[k][ty * 4];
            float4 bv = *(const float4*)&Bs[k][tx * 4];
            float a[4] = {av.x, av.y, av.z, av.w};
            float c[4] = {bv.x, bv.y, bv.z, bv.w};
            #pragma unroll
            for (int i = 0; i < 4; i++)
                #pragma unroll
                for (int j = 0; j < 4; j++)
                    acc[i][j] = fmaf(a[i], c[j], acc[i][j]);
        }
        __syncthreads();
    }
    #pragma unroll
    for (int i = 0; i < 4; i++) {
        float4 v = {acc[i][0], acc[i][1], acc[i][2], acc[i][3]};
        *(float4*)&xz[((size_t)b * D2 + d0 + ty * 4 + i) * LL + l0 + tx * 4] = v;
    }
}

// ---------------------------------------------------------------------------
// Depthwise causal conv(4) + bias + SiLU on x-half of xz -> xc
// ---------------------------------------------------------------------------
__global__ __launch_bounds__(256) void conv_silu_k(const float* __restrict__ xz,
                                                   const float* __restrict__ cw,
                                                   const float* __restrict__ cb,
                                                   float* __restrict__ xc) {
    const int row = blockIdx.x;             // 0..B*DI-1
    const int b = row / DI, d = row % DI;
    const float* xr = xz + ((size_t)b * D2 + d) * LL;
    float w0 = cw[d * 4 + 0], w1 = cw[d * 4 + 1];
    float w2 = cw[d * 4 + 2], w3 = cw[d * 4 + 3];
    float bias = cb[d];
    const int l0 = threadIdx.x * 8;
    float buf[11];
    #pragma unroll
    for (int i = 0; i < 11; i++) {
        int l = l0 - 3 + i;
        buf[i] = (l >= 0) ? xr[l] : 0.f;
    }
    float* out = xc + ((size_t)b * DI + d) * LL;
    #pragma unroll
    for (int j = 0; j < 8; j++) {
        float s = fmaf(buf[j], w0, fmaf(buf[j + 1], w1,
                  fmaf(buf[j + 2], w2, fmaf(buf[j + 3], w3, bias))));
        out[l0 + j] = s / (1.f + expf(-s));
    }
}

// ---------------------------------------------------------------------------
// x_dbl partials: part[seg][b][k][l] = sum_{d in seg} xc[b][d][l]*Wx[k][d]
// ---------------------------------------------------------------------------
__global__ __launch_bounds__(256) void xproj_partial_k(const float* __restrict__ xc,
                                                       const float* __restrict__ Wx,
                                                       float* __restrict__ part) {
    const int blk = blockIdx.x;            // b*64 + seg*8 + lt
    const int b = blk >> 6, seg = (blk >> 3) & 7, lt = blk & 7;
    const int l = lt * 256 + threadIdx.x;
    __shared__ float w[KX][64];
    float acc[KX] = {};
    const float* xb = xc + (size_t)b * DI * LL;
    for (int dc = 0; dc < 256; dc += 64) {
        const int dbase = seg * 256 + dc;
        __syncthreads();
        for (int i = threadIdx.x; i < KX * 64; i += 256) {
            int kk = i >> 6, dd = i & 63;
            w[kk][dd] = Wx[(size_t)kk * DI + dbase + dd];
        }
        __syncthreads();
        for (int dd = 0; dd < 64; dd++) {
            float v = xb[(size_t)(dbase + dd) * LL + l];
            #pragma unroll
            for (int kk = 0; kk < KX; kk++) acc[kk] = fmaf(v, w[kk][dd], acc[kk]);
        }
    }
    for (int kk = 0; kk < KX; kk++)
        part[(((size_t)seg * BB + b) * KX + kk) * LL + l] = acc[kk];
}

__global__ __launch_bounds__(256) void xproj_reduce_k(const float* __restrict__ part,
                                                      float* __restrict__ xdbl) {
    const int i = blockIdx.x * 256 + threadIdx.x;   // B*KX*L = 135168
    float s = 0.f;
    #pragma unroll
    for (int seg = 0; seg < 8; seg++) s += part[(size_t)seg * BB * KX * LL + i];
    xdbl[i] = s;
}

// ---------------------------------------------------------------------------
// Prep: dt[b,d,l] = softplus(Wdt[d]*dtr[b,l] + bdt[d])  -> stored in xz z-half
//       zs[b,d,l] = silu(z[b,d,l])                      -> stored in xz x-half
// (x-half dead after conv; z-half dead after this kernel. NO __restrict__ on
//  xz: dt write aliases the z read.)
// ---------------------------------------------------------------------------
__global__ __launch_bounds__(256) void prep_k(float* xz,
                                              const float* __restrict__ xdbl,
                                              const float* __restrict__ Wdt,
                                              const float* __restrict__ bdt) {
    const int row = blockIdx.x;              // b*DI + d
    const int b = row >> 11, d = row & (DI - 1);
    const float wdt = Wdt[d], bv = bdt[d];
    const float* dtr = xdbl + (size_t)b * KX * LL;         // row 0 = dt_raw
    float* zrow  = xz + ((size_t)b * D2 + DI + d) * LL;    // z in, dt out
    float* zsrow = xz + ((size_t)b * D2 + d) * LL;         // zs out
    const int l0 = threadIdx.x * 8;

    float4 dv0 = *(const float4*)&dtr[l0];
    float4 dv1 = *(const float4*)&dtr[l0 + 4];
    float4 zv0 = *(const float4*)&zrow[l0];
    float4 zv1 = *(const float4*)&zrow[l0 + 4];
    float dvv[8] = {dv0.x, dv0.y, dv0.z, dv0.w, dv1.x, dv1.y, dv1.z, dv1.w};
    float zvv[8] = {zv0.x, zv0.y, zv0.z, zv0.w, zv1.x, zv1.y, zv1.z, zv1.w};
    float dto[8], zso[8];
    #pragma unroll
    for (int k = 0; k < 8; k++) {
        float v = fmaf(wdt, dvv[k], bv);
        dto[k] = fmaxf(v, 0.f) + log1pf(expf(-fabsf(v)));   // stable softplus
        float z = zvv[k];
        zso[k] = z / (1.f + expf(-z));
    }
    *(float4*)&zrow[l0]      = make_float4(dto[0], dto[1], dto[2], dto[3]);
    *(float4*)&zrow[l0 + 4]  = make_float4(dto[4], dto[5], dto[6], dto[7]);
    *(float4*)&zsrow[l0]     = make_float4(zso[0], zso[1], zso[2], zso[3]);
    *(float4*)&zsrow[l0 + 4] = make_float4(zso[4], zso[5], zso[6], zso[7]);
}

// ---------------------------------------------------------------------------
// Scan pass 1: per chunk c, local scan with h_in = 0. Outputs terminal h
// (hloc) and chunk dt-sum (decay = exp(a*sumdt), exact since dA=exp(a*dt)).
// ---------------------------------------------------------------------------
__global__ __launch_bounds__(256) void scan1_k(const float* __restrict__ xz,
                                               const float* __restrict__ xc,
                                               const float* __restrict__ xdbl,
                                               const float* __restrict__ Alog,
                                               float* __restrict__ hloc,
                                               float* __restrict__ sumdt) {
    const int blk = blockIdx.x;          // c*256 + b*128 + dblk
    const int c = blk >> 8;
    const int b = (blk >> 7) & 1;
    const int d0 = (blk & 127) * 16;
    const int tid = threadIdx.x, dl = tid >> 4, n = tid & 15;
    const int d = d0 + dl;
    const float a2 = -expf(Alog[(size_t)d * DS + n]) * 1.44269504f;

    __shared__ float sdt[16][68], sx[16][68], sB[16][68];
    float h = 0.f, dts = 0.f;
    const int r = tid >> 4, cc = (tid & 15) * 4;
    const int lbase = c * LC;

    for (int c0 = 0; c0 < LC; c0 += 64) {
        __syncthreads();
        const int lofs = lbase + c0 + cc;
        *(float4*)&sdt[r][cc] = *(const float4*)&xz  [((size_t)b * D2 + DI + d0 + r) * LL + lofs];
        *(float4*)&sx [r][cc] = *(const float4*)&xc  [((size_t)b * DI + d0 + r) * LL + lofs];
        *(float4*)&sB [r][cc] = *(const float4*)&xdbl[((size_t)b * KX + 1 + r) * LL + lofs];
        __syncthreads();
        #pragma unroll 4
        for (int ll = 0; ll < 64; ll++) {
            float dt = sdt[dl][ll];
            float dA = exp2f(a2 * dt);
            h = fmaf(dA, h, dt * sx[dl][ll] * sB[n][ll]);
            dts += dt;
        }
    }
    hloc[(((size_t)c * BB + b) * DI + d) * DS + n] = h;
    if (n == 0) sumdt[((size_t)c * BB + b) * DI + d] = dts;
}

// ---------------------------------------------------------------------------
// Combine: serial over 16 chunk boundaries (65536 independent states).
// ---------------------------------------------------------------------------
__global__ __launch_bounds__(256) void combine_k(const float* __restrict__ hloc,
                                                 const float* __restrict__ sumdt,
                                                 const float* __restrict__ Alog,
                                                 float* __restrict__ hin) {
    const int i = blockIdx.x * 256 + threadIdx.x;   // (b*DI+d)*16+n
    const int n = i & 15;
    const int bd = i >> 4;                          // b*DI+d
    const int d = bd & (DI - 1);
    const float a2 = -expf(Alog[(size_t)d * DS + n]) * 1.44269504f;
    float h = 0.f;
    for (int c = 0; c < NC; c++) {
        size_t idx = ((size_t)c * BB * DI + bd) * DS + n;
        hin[idx] = h;
        float P = exp2f(a2 * sumdt[(size_t)c * BB * DI + bd]);
        h = fmaf(P, h, hloc[idx]);
    }
}

// ---------------------------------------------------------------------------
// Scan pass 2: re-run each chunk with correct h_in, emit
// y = (sum_n h*C + x*Dskip) * silu(z), in-place into xc via LDS tile.
// ---------------------------------------------------------------------------
__global__ __launch_bounds__(256) void scan2_k(const float* __restrict__ xz,
                                               float* __restrict__ xc,
                                               const float* __restrict__ xdbl,
                                               const float* __restrict__ Alog,
                                               const float* __restrict__ Dskip,
                                               const float* __restrict__ hin) {
    const int blk = blockIdx.x;
    const int c = blk >> 8;
    const int b = (blk >> 7) & 1;
    const int d0 = (blk & 127) * 16;
    const int tid = threadIdx.x, dl = tid >> 4, n = tid & 15;
    const int d = d0 + dl;
    const float a2 = -expf(Alog[(size_t)d * DS + n]) * 1.44269504f;
    const float dsk = Dskip[d];

    __shared__ float sdt[16][68], sx[16][68], sB[16][68], sC[16][68],
                     szs[16][68], sy[16][68];
    float h = hin[(((size_t)c * BB + b) * DI + d) * DS + n];
    const int r = tid >> 4, cc = (tid & 15) * 4;
    const int lbase = c * LC;

    for (int c0 = 0; c0 < LC; c0 += 64) {
        __syncthreads();
        const int lofs = lbase + c0 + cc;
        *(float4*)&sdt[r][cc] = *(const float4*)&xz  [((size_t)b * D2 + DI + d0 + r) * LL + lofs];
        *(float4*)&sx [r][cc] = *(const float4*)&xc  [((size_t)b * DI + d0 + r) * LL + lofs];
        *(float4*)&szs[r][cc] = *(const float4*)&xz  [((size_t)b * D2 + d0 + r) * LL + lofs];
        *(float4*)&sB [r][cc] = *(const float4*)&xdbl[((size_t)b * KX + 1 + r) * LL + lofs];
        *(float4*)&sC [r][cc] = *(const float4*)&xdbl[((size_t)b * KX + 17 + r) * LL + lofs];
        __syncthreads();
        for (int ll = 0; ll < 64; ll++) {
            float dt = sdt[dl][ll];
            float xv = sx[dl][ll];
            float dA = exp2f(a2 * dt);
            h = fmaf(dA, h, dt * xv * sB[n][ll]);
            float contrib = h * sC[n][ll];
            contrib += __shfl_xor(contrib, 1);
            contrib += __shfl_xor(contrib, 2);
            contrib += __shfl_xor(contrib, 4);
            contrib += __shfl_xor(contrib, 8);
            if (n == 0) {
                float yv = fmaf(xv, dsk, contrib);
                sy[dl][ll] = yv * szs[dl][ll];
            }
        }
        __syncthreads();
        *(float4*)&xc[((size_t)b * DI + d0 + r) * LL + lofs] = *(const float4*)&sy[r][cc];
    }
}

// ---------------------------------------------------------------------------
// GEMM2: out[b][l][m] = sum_d y[b][d][l] * W_out[m][d]
// ---------------------------------------------------------------------------
__global__ __launch_bounds__(256) void gemm2_k(const float* __restrict__ y,
                                               const float* __restrict__ Wout,
                                               float* __restrict__ out) {
    __shared__ float Ys[32][68];  // [k][l]
    __shared__ float Ws[32][68];  // [k][m]
    const int bn = blockIdx.x;    // m tile (16)
    const int bm = blockIdx.y;    // bl tile (64)
    const int tid = threadIdx.x;
    const int tx = tid & 15, ty = tid >> 4;
    const int bl0 = bm * 64, m0 = bn * 64;
    const int b = bl0 >> 11, l0 = bl0 & (LL - 1);

    float acc[4][4] = {};
    for (int k0 = 0; k0 < DI; k0 += 32) {
        #pragma unroll
        for (int i = 0; i < 2; i++) {
            int idx = tid + i * 256;
            int kk = idx >> 4;                // 0..31
            int c4 = (idx & 15) * 4;          // 0..60
            float4 v = *(const float4*)&y[((size_t)b * DI + k0 + kk) * LL + l0 + c4];
            *(float4*)&Ys[kk][c4] = v;
            int row = idx >> 3;               // 0..63
            int k4 = (idx & 7) * 4;           // 0..28
            float4 w = *(const float4*)&Wout[(size_t)(m0 + row) * DI + k0 + k4];
            Ws[k4 + 0][row] = w.x; Ws[k4 + 1][row] = w.y;
            Ws[k4 + 2][row] = w.z; Ws[k4 + 3][row] = w.w;
        }
        __syncthreads();
        #pragma unroll
        for (int k = 0; k < 32; k++) {
            float4 av = *(const float4*)&Ys[k][ty * 4];
            float4 bw = *(const float4*)&Ws[k][tx * 4];
            float a[4] = {av.x, av.y, av.z, av.w};
            float c[4] = {bw.x, bw.y, bw.z, bw.w};
            #pragma unroll
            for (int i = 0; i < 4; i++)
                #pragma unroll
                for (int j = 0; j < 4; j++)
                    acc[i][j] = fmaf(a[i], c[j], acc[i][j]);
        }
        __syncthreads();
    }
    #pragma unroll
    for (int i = 0; i < 4; i++) {
        float4 v = {acc[i][0], acc[i][1], acc[i][2], acc[i][3]};
        *(float4*)&out[((size_t)b * LL + l0 + ty * 4 + i) * DM + m0 + tx * 4] = v;
    }
}

// ---------------------------------------------------------------------------
extern "C" void kernel_launch(void* const* d_in, const int* in_sizes, int n_in,
                              void* d_out, int out_size, void* d_ws, size_t ws_size,
                              hipStream_t stream) {
    const float* hs   = (const float*)d_in[0];
    const float* Win  = (const float*)d_in[1];
    const float* cw   = (const float*)d_in[2];
    const float* cb   = (const float*)d_in[3];
    const float* Wx   = (const float*)d_in[4];
    const float* Wdt  = (const float*)d_in[5];
    const float* bdt  = (const float*)d_in[6];
    const float* Alog = (const float*)d_in[7];
    const float* Dsk  = (const float*)d_in[8];
    const float* Wout = (const float*)d_in[9];
    float* out = (float*)d_out;

    float* xz    = (float*)d_ws;                           // B*4096*L
    float* xc    = xz   + (size_t)BB * D2 * LL;            // B*DI*L
    float* part  = xc   + (size_t)BB * DI * LL;            // 8*B*KX*L
    float* xdbl  = part + (size_t)8 * BB * KX * LL;        // B*KX*L
    float* hin   = xdbl + (size_t)BB * KX * LL;            // NC*B*DI*DS
    float* sumdt = hin  + (size_t)NC * BB * DI * DS;       // NC*B*DI
    float* hloc  = part;                                   // reuse: part dead after xproj_reduce

    gemm1_k<<<dim3(64, 64), 256, 0, stream>>>(hs, Win, xz);
    conv_silu_k<<<BB * DI, 256, 0, stream>>>(xz, cw, cb, xc);
    xproj_partial_k<<<128, 256, 0, stream>>>(xc, Wx, part);
    xproj_reduce_k<<<(BB * KX * LL) / 256, 256, 0, stream>>>(part, xdbl);
    prep_k<<<BB * DI, 256, 0, stream>>>(xz, xdbl, Wdt, bdt);
    scan1_k<<<NC * BB * 128, 256, 0, stream>>>(xz, xc, xdbl, Alog, hloc, sumdt);
    combine_k<<<(BB * DI * DS) / 256, 256, 0, stream>>>(hloc, sumdt, Alog, hin);
    scan2_k<<<NC * BB * 128, 256, 0, stream>>>(xz, xc, xdbl, Alog, Dsk, hin);
    gemm2_k<<<dim3(16, 64), 256, 0, stream>>>(xc, Wout, out);
}

// Round 3
// 464.305 us; speedup vs baseline: 4.3057x; 2.2209x over previous
//
#include <hip/hip_runtime.h>
#include <hip/hip_bf16.h>
#include <math.h>

#define BB 2
#define LL 2048
#define DM 1024
#define DS 16
#define DI 2048
#define KX 33          // 1 + 2*D_STATE
#define D2 (2*DI)      // 4096
#define NC 16          // scan chunks
#define LC 128         // chunk length (NC*LC == LL)

typedef __attribute__((ext_vector_type(8))) short short8v;   // 8 bf16 (4 VGPRs)
typedef __attribute__((ext_vector_type(4))) float f32x4;

__device__ __forceinline__ void gload16(const void* g, void* l) {
    __builtin_amdgcn_global_load_lds((const __attribute__((address_space(1))) void*)g,
                                     (__attribute__((address_space(3))) void*)l,
                                     16, 0, 0);
}

__device__ __forceinline__ ushort tobf(float v) {
    __hip_bfloat16 h = __float2bfloat16(v);
    return *(ushort*)&h;
}

// ---------------------------------------------------------------------------
// fp32 -> bf16 (RNE) conversion, 8 elems/thread
// ---------------------------------------------------------------------------
__global__ __launch_bounds__(256) void cvt_bf16_k(const float* __restrict__ in,
                                                  ushort* __restrict__ o, int n8) {
    int i = blockIdx.x * 256 + threadIdx.x;
    if (i >= n8) return;
    float4 a = *(const float4*)&in[(size_t)i * 8];
    float4 b = *(const float4*)&in[(size_t)i * 8 + 4];
    float v[8] = {a.x, a.y, a.z, a.w, b.x, b.y, b.z, b.w};
    ushort u[8];
    #pragma unroll
    for (int j = 0; j < 8; j++) u[j] = tobf(v[j]);
    *(ushort4*)&o[(size_t)i * 8]     = make_ushort4(u[0], u[1], u[2], u[3]);
    *(ushort4*)&o[(size_t)i * 8 + 4] = make_ushort4(u[4], u[5], u[6], u[7]);
}

// ---------------------------------------------------------------------------
// NT bf16 MFMA GEMM: C[M][N] = sum_k A[M][K]*B[N][K], both row-major K-contig.
// 128x128 tile, 4 waves (2x2), 4x4 16x16x32 fragments per wave, BK=32,
// global_load_lds width-16 staging (m97 structure).
// MODE 0: C row=d, col=bl -> xz[((col>>11)*D2 + row)*LL + (col&2047)]
// MODE 1: C row=bl, col=m -> out[row*DM + col]
// ---------------------------------------------------------------------------
template<int K, int MODE>
__global__ __launch_bounds__(256) void mfma_nt_k(const ushort* __restrict__ A,
                                                 const ushort* __restrict__ Bm,
                                                 float* __restrict__ C) {
    __shared__ ushort Als[128][32];
    __shared__ ushort Bls[128][32];
    const int n0 = blockIdx.x * 128;
    const int m0 = blockIdx.y * 128;
    const int tid = threadIdx.x;
    const int w = tid >> 6, lane = tid & 63;
    const int wr = (w >> 1) * 64, wc = (w & 1) * 64;
    const int lrow = lane & 15;        // fragment row
    const int kq = lane >> 4;          // fragment k-quad (8 elems)

    const int srow = (lane >> 2);      // 0..15 within a 16-row staging chunk
    const int skof = (lane & 3) * 8;   // k offset in elems for staging

    f32x4 acc[4][4] = {};
    for (int k0 = 0; k0 < K; k0 += 32) {
        #pragma unroll
        for (int j = 0; j < 2; j++) {
            const int rbase = w * 32 + j * 16;
            gload16(&A [(size_t)(m0 + rbase + srow) * K + k0 + skof], &Als[rbase][0]);
            gload16(&Bm[(size_t)(n0 + rbase + srow) * K + k0 + skof], &Bls[rbase][0]);
        }
        __syncthreads();
        short8v af[4], bf[4];
        #pragma unroll
        for (int i = 0; i < 4; i++) {
            af[i] = *(const short8v*)&Als[wr + i * 16 + lrow][kq * 8];
            bf[i] = *(const short8v*)&Bls[wc + i * 16 + lrow][kq * 8];
        }
        #pragma unroll
        for (int i = 0; i < 4; i++)
            #pragma unroll
            for (int jn = 0; jn < 4; jn++)
                acc[i][jn] = __builtin_amdgcn_mfma_f32_16x16x32_bf16(af[i], bf[jn], acc[i][jn], 0, 0, 0);
        __syncthreads();
    }
    // epilogue: C/D layout col=lane&15, row=(lane>>4)*4+reg
    #pragma unroll
    for (int i = 0; i < 4; i++) {
        #pragma unroll
        for (int jn = 0; jn < 4; jn++) {
            #pragma unroll
            for (int r = 0; r < 4; r++) {
                int row = m0 + wr + i * 16 + (lane >> 4) * 4 + r;
                int col = n0 + wc + jn * 16 + (lane & 15);
                size_t off;
                if constexpr (MODE == 0)
                    off = ((size_t)(col >> 11) * D2 + row) * LL + (col & (LL - 1));
                else
                    off = (size_t)row * DM + col;
                C[off] = acc[i][jn][r];
            }
        }
    }
}

// ---------------------------------------------------------------------------
// Depthwise causal conv(4) + bias + SiLU on x-half of xz -> xc
// ---------------------------------------------------------------------------
__global__ __launch_bounds__(256) void conv_silu_k(const float* __restrict__ xz,
                                                   const float* __restrict__ cw,
                                                   const float* __restrict__ cb,
                                                   float* __restrict__ xc) {
    const int row = blockIdx.x;             // 0..B*DI-1
    const int b = row / DI, d = row % DI;
    const float* xr = xz + ((size_t)b * D2 + d) * LL;
    float w0 = cw[d * 4 + 0], w1 = cw[d * 4 + 1];
    float w2 = cw[d * 4 + 2], w3 = cw[d * 4 + 3];
    float bias = cb[d];
    const int l0 = threadIdx.x * 8;
    float buf[11];
    #pragma unroll
    for (int i = 0; i < 11; i++) {
        int l = l0 - 3 + i;
        buf[i] = (l >= 0) ? xr[l] : 0.f;
    }
    float* out = xc + ((size_t)b * DI + d) * LL;
    #pragma unroll
    for (int j = 0; j < 8; j++) {
        float s = fmaf(buf[j], w0, fmaf(buf[j + 1], w1,
                  fmaf(buf[j + 2], w2, fmaf(buf[j + 3], w3, bias))));
        out[l0 + j] = s / (1.f + expf(-s));
    }
}

// ---------------------------------------------------------------------------
// x_dbl partials: part[seg][b][k][l] = sum_{d in seg} xc[b][d][l]*Wx[k][d]
// ---------------------------------------------------------------------------
__global__ __launch_bounds__(256) void xproj_partial_k(const float* __restrict__ xc,
                                                       const float* __restrict__ Wx,
                                                       float* __restrict__ part) {
    const int blk = blockIdx.x;            // b*64 + seg*8 + lt
    const int b = blk >> 6, seg = (blk >> 3) & 7, lt = blk & 7;
    const int l = lt * 256 + threadIdx.x;
    __shared__ float w[KX][64];
    float acc[KX] = {};
    const float* xb = xc + (size_t)b * DI * LL;
    for (int dc = 0; dc < 256; dc += 64) {
        const int dbase = seg * 256 + dc;
        __syncthreads();
        for (int i = threadIdx.x; i < KX * 64; i += 256) {
            int kk = i >> 6, dd = i & 63;
            w[kk][dd] = Wx[(size_t)kk * DI + dbase + dd];
        }
        __syncthreads();
        for (int dd = 0; dd < 64; dd++) {
            float v = xb[(size_t)(dbase + dd) * LL + l];
            #pragma unroll
            for (int kk = 0; kk < KX; kk++) acc[kk] = fmaf(v, w[kk][dd], acc[kk]);
        }
    }
    for (int kk = 0; kk < KX; kk++)
        part[(((size_t)seg * BB + b) * KX + kk) * LL + l] = acc[kk];
}

__global__ __launch_bounds__(256) void xproj_reduce_k(const float* __restrict__ part,
                                                      float* __restrict__ xdbl) {
    const int i = blockIdx.x * 256 + threadIdx.x;   // B*KX*L = 135168
    float s = 0.f;
    #pragma unroll
    for (int seg = 0; seg < 8; seg++) s += part[(size_t)seg * BB * KX * LL + i];
    xdbl[i] = s;
}

// ---------------------------------------------------------------------------
// Prep: dt = softplus(Wdt*dtr + bdt) -> xz z-half; zs = silu(z) -> xz x-half
// ---------------------------------------------------------------------------
__global__ __launch_bounds__(256) void prep_k(float* xz,
                                              const float* __restrict__ xdbl,
                                              const float* __restrict__ Wdt,
                                              const float* __restrict__ bdt) {
    const int row = blockIdx.x;              // b*DI + d
    const int b = row >> 11, d = row & (DI - 1);
    const float wdt = Wdt[d], bv = bdt[d];
    const float* dtr = xdbl + (size_t)b * KX * LL;         // row 0 = dt_raw
    float* zrow  = xz + ((size_t)b * D2 + DI + d) * LL;    // z in, dt out
    float* zsrow = xz + ((size_t)b * D2 + d) * LL;         // zs out
    const int l0 = threadIdx.x * 8;

    float4 dv0 = *(const float4*)&dtr[l0];
    float4 dv1 = *(const float4*)&dtr[l0 + 4];
    float4 zv0 = *(const float4*)&zrow[l0];
    float4 zv1 = *(const float4*)&zrow[l0 + 4];
    float dvv[8] = {dv0.x, dv0.y, dv0.z, dv0.w, dv1.x, dv1.y, dv1.z, dv1.w};
    float zvv[8] = {zv0.x, zv0.y, zv0.z, zv0.w, zv1.x, zv1.y, zv1.z, zv1.w};
    float dto[8], zso[8];
    #pragma unroll
    for (int k = 0; k < 8; k++) {
        float v = fmaf(wdt, dvv[k], bv);
        dto[k] = fmaxf(v, 0.f) + log1pf(expf(-fabsf(v)));   // stable softplus
        float z = zvv[k];
        zso[k] = z / (1.f + expf(-z));
    }
    *(float4*)&zrow[l0]      = make_float4(dto[0], dto[1], dto[2], dto[3]);
    *(float4*)&zrow[l0 + 4]  = make_float4(dto[4], dto[5], dto[6], dto[7]);
    *(float4*)&zsrow[l0]     = make_float4(zso[0], zso[1], zso[2], zso[3]);
    *(float4*)&zsrow[l0 + 4] = make_float4(zso[4], zso[5], zso[6], zso[7]);
}

// ---------------------------------------------------------------------------
// Scan pass 1: per-chunk local scan with h_in = 0 -> terminal h + dt-sum.
// ---------------------------------------------------------------------------
__global__ __launch_bounds__(256) void scan1_k(const float* __restrict__ xz,
                                               const float* __restrict__ xc,
                                               const float* __restrict__ xdbl,
                                               const float* __restrict__ Alog,
                                               float* __restrict__ hloc,
                                               float* __restrict__ sumdt) {
    const int blk = blockIdx.x;          // c*256 + b*128 + dblk
    const int c = blk >> 8;
    const int b = (blk >> 7) & 1;
    const int d0 = (blk & 127) * 16;
    const int tid = threadIdx.x, dl = tid >> 4, n = tid & 15;
    const int d = d0 + dl;
    const float a2 = -expf(Alog[(size_t)d * DS + n]) * 1.44269504f;

    __shared__ float sdt[16][68], sx[16][68], sB[16][68];
    float h = 0.f, dts = 0.f;
    const int r = tid >> 4, cc = (tid & 15) * 4;
    const int lbase = c * LC;

    for (int c0 = 0; c0 < LC; c0 += 64) {
        __syncthreads();
        const int lofs = lbase + c0 + cc;
        *(float4*)&sdt[r][cc] = *(const float4*)&xz  [((size_t)b * D2 + DI + d0 + r) * LL + lofs];
        *(float4*)&sx [r][cc] = *(const float4*)&xc  [((size_t)b * DI + d0 + r) * LL + lofs];
        *(float4*)&sB [r][cc] = *(const float4*)&xdbl[((size_t)b * KX + 1 + r) * LL + lofs];
        __syncthreads();
        #pragma unroll 4
        for (int ll = 0; ll < 64; ll++) {
            float dt = sdt[dl][ll];
            float dA = exp2f(a2 * dt);
            h = fmaf(dA, h, dt * sx[dl][ll] * sB[n][ll]);
            dts += dt;
        }
    }
    hloc[(((size_t)c * BB + b) * DI + d) * DS + n] = h;
    if (n == 0) sumdt[((size_t)c * BB + b) * DI + d] = dts;
}

// ---------------------------------------------------------------------------
// Combine: serial over 16 chunk boundaries (65536 independent states).
// ---------------------------------------------------------------------------
__global__ __launch_bounds__(256) void combine_k(const float* __restrict__ hloc,
                                                 const float* __restrict__ sumdt,
                                                 const float* __restrict__ Alog,
                                                 float* __restrict__ hin) {
    const int i = blockIdx.x * 256 + threadIdx.x;   // (b*DI+d)*16+n
    const int n = i & 15;
    const int bd = i >> 4;                          // b*DI+d
    const int d = bd & (DI - 1);
    const float a2 = -expf(Alog[(size_t)d * DS + n]) * 1.44269504f;
    float h = 0.f;
    for (int c = 0; c < NC; c++) {
        size_t idx = ((size_t)c * BB * DI + bd) * DS + n;
        hin[idx] = h;
        float P = exp2f(a2 * sumdt[(size_t)c * BB * DI + bd]);
        h = fmaf(P, h, hloc[idx]);
    }
}

// ---------------------------------------------------------------------------
// Scan pass 2: correct h_in, y = (sum_n h*C + x*Dskip)*silu(z),
// emitted as TRANSPOSED bf16 ybf[bl][d] (K-contiguous for GEMM2 MFMA).
// ---------------------------------------------------------------------------
__global__ __launch_bounds__(256) void scan2_k(const float* __restrict__ xz,
                                               const float* __restrict__ xc,
                                               const float* __restrict__ xdbl,
                                               const float* __restrict__ Alog,
                                               const float* __restrict__ Dskip,
                                               const float* __restrict__ hin,
                                               ushort* __restrict__ ybf) {
    const int blk = blockIdx.x;
    const int c = blk >> 8;
    const int b = (blk >> 7) & 1;
    const int d0 = (blk & 127) * 16;
    const int tid = threadIdx.x, dl = tid >> 4, n = tid & 15;
    const int d = d0 + dl;
    const float a2 = -expf(Alog[(size_t)d * DS + n]) * 1.44269504f;
    const float dsk = Dskip[d];

    __shared__ float sdt[16][68], sx[16][68], sB[16][68], sC[16][68],
                     szs[16][68], sy[16][68];
    float h = hin[(((size_t)c * BB + b) * DI + d) * DS + n];
    const int r = tid >> 4, cc = (tid & 15) * 4;
    const int lbase = c * LC;

    for (int c0 = 0; c0 < LC; c0 += 64) {
        __syncthreads();
        const int lofs = lbase + c0 + cc;
        *(float4*)&sdt[r][cc] = *(const float4*)&xz  [((size_t)b * D2 + DI + d0 + r) * LL + lofs];
        *(float4*)&sx [r][cc] = *(const float4*)&xc  [((size_t)b * DI + d0 + r) * LL + lofs];
        *(float4*)&szs[r][cc] = *(const float4*)&xz  [((size_t)b * D2 + d0 + r) * LL + lofs];
        *(float4*)&sB [r][cc] = *(const float4*)&xdbl[((size_t)b * KX + 1 + r) * LL + lofs];
        *(float4*)&sC [r][cc] = *(const float4*)&xdbl[((size_t)b * KX + 17 + r) * LL + lofs];
        __syncthreads();
        for (int ll = 0; ll < 64; ll++) {
            float dt = sdt[dl][ll];
            float xv = sx[dl][ll];
            float dA = exp2f(a2 * dt);
            h = fmaf(dA, h, dt * xv * sB[n][ll]);
            float contrib = h * sC[n][ll];
            contrib += __shfl_xor(contrib, 1);
            contrib += __shfl_xor(contrib, 2);
            contrib += __shfl_xor(contrib, 4);
            contrib += __shfl_xor(contrib, 8);
            if (n == 0) {
                float yv = fmaf(xv, dsk, contrib);
                sy[dl][ll] = yv * szs[dl][ll];
            }
        }
        __syncthreads();
        {   // transposed bf16 write: ybf[(b*LL + l)][d]
            int lw = tid >> 2;             // 0..63
            int dq = (tid & 3) * 4;        // 0,4,8,12
            ushort4 u = make_ushort4(tobf(sy[dq + 0][lw]), tobf(sy[dq + 1][lw]),
                                     tobf(sy[dq + 2][lw]), tobf(sy[dq + 3][lw]));
            *(ushort4*)&ybf[((size_t)b * LL + lbase + c0 + lw) * DI + d0 + dq] = u;
        }
    }
}

// ---------------------------------------------------------------------------
extern "C" void kernel_launch(void* const* d_in, const int* in_sizes, int n_in,
                              void* d_out, int out_size, void* d_ws, size_t ws_size,
                              hipStream_t stream) {
    const float* hs   = (const float*)d_in[0];
    const float* Win  = (const float*)d_in[1];
    const float* cw   = (const float*)d_in[2];
    const float* cb   = (const float*)d_in[3];
    const float* Wx   = (const float*)d_in[4];
    const float* Wdt  = (const float*)d_in[5];
    const float* bdt  = (const float*)d_in[6];
    const float* Alog = (const float*)d_in[7];
    const float* Dsk  = (const float*)d_in[8];
    const float* Wout = (const float*)d_in[9];
    float* out = (float*)d_out;

    float* xz    = (float*)d_ws;                           // 16,777,216 f
    float* xc    = xz    + (size_t)BB * D2 * LL;           //  8,388,608 f
    float* part  = xc    + (size_t)BB * DI * LL;           //  1,081,344 f (hloc; later Woutb)
    float* xdbl  = part  + (size_t)8 * BB * KX * LL;       //    135,168 f
    float* hin   = xdbl  + (size_t)BB * KX * LL;           //  1,048,576 f
    float* sumdt = hin   + (size_t)NC * BB * DI * DS;      //     65,536 f
    float* convf = sumdt + (size_t)NC * BB * DI;           //  4,194,304 f (Winb+hsb / ybf)
    float* hloc  = part;

    ushort* Winb  = (ushort*)convf;                        // 4,194,304 u16
    ushort* hsb   = Winb + (size_t)D2 * DM;                // 4,194,304 u16
    ushort* ybf   = (ushort*)convf;                        // aliases Winb+hsb (dead after gemm1)
    ushort* Woutb = (ushort*)part;                         // aliases hloc (dead after combine)

    cvt_bf16_k<<<2048, 256, 0, stream>>>(Win, Winb, (D2 * DM) / 8);
    cvt_bf16_k<<<2048, 256, 0, stream>>>(hs, hsb, (BB * LL * DM) / 8);
    mfma_nt_k<DM, 0><<<dim3(32, 32), 256, 0, stream>>>(Winb, hsb, xz);
    conv_silu_k<<<BB * DI, 256, 0, stream>>>(xz, cw, cb, xc);
    xproj_partial_k<<<128, 256, 0, stream>>>(xc, Wx, part);
    xproj_reduce_k<<<(BB * KX * LL) / 256, 256, 0, stream>>>(part, xdbl);
    prep_k<<<BB * DI, 256, 0, stream>>>(xz, xdbl, Wdt, bdt);
    scan1_k<<<NC * BB * 128, 256, 0, stream>>>(xz, xc, xdbl, Alog, hloc, sumdt);
    combine_k<<<(BB * DI * DS) / 256, 256, 0, stream>>>(hloc, sumdt, Alog, hin);
    cvt_bf16_k<<<1024, 256, 0, stream>>>(Wout, Woutb, (DM * DI) / 8);
    scan2_k<<<NC * BB * 128, 256, 0, stream>>>(xz, xc, xdbl, Alog, Dsk, hin, ybf);
    mfma_nt_k<DI, 1><<<dim3(8, 32), 256, 0, stream>>>(ybf, Woutb, out);
}

// Round 4
// 385.612 us; speedup vs baseline: 5.1844x; 1.2041x over previous
//
#include <hip/hip_runtime.h>
#include <hip/hip_bf16.h>
#include <math.h>

#define BB 2
#define LL 2048
#define DM 1024
#define DS 16
#define DI 2048
#define KX 33          // 1 + 2*D_STATE
#define D2 (2*DI)      // 4096
#define NC 32          // scan chunks
#define LC 64          // chunk length (NC*LC == LL)

typedef __attribute__((ext_vector_type(8))) short short8v;   // 8 bf16 (4 VGPRs)
typedef __attribute__((ext_vector_type(4))) float f32x4;

__device__ __forceinline__ void gload16(const void* g, void* l) {
    __builtin_amdgcn_global_load_lds((const __attribute__((address_space(1))) void*)g,
                                     (__attribute__((address_space(3))) void*)l,
                                     16, 0, 0);
}

__device__ __forceinline__ ushort tobf(float v) {
    __hip_bfloat16 h = __float2bfloat16(v);
    return *(ushort*)&h;
}

// ---------------------------------------------------------------------------
// fp32 -> bf16 (RNE) conversion, 8 elems/thread
// ---------------------------------------------------------------------------
__global__ __launch_bounds__(256) void cvt_bf16_k(const float* __restrict__ in,
                                                  ushort* __restrict__ o, int n8) {
    int i = blockIdx.x * 256 + threadIdx.x;
    if (i >= n8) return;
    float4 a = *(const float4*)&in[(size_t)i * 8];
    float4 b = *(const float4*)&in[(size_t)i * 8 + 4];
    float v[8] = {a.x, a.y, a.z, a.w, b.x, b.y, b.z, b.w};
    ushort u[8];
    #pragma unroll
    for (int j = 0; j < 8; j++) u[j] = tobf(v[j]);
    *(ushort4*)&o[(size_t)i * 8]     = make_ushort4(u[0], u[1], u[2], u[3]);
    *(ushort4*)&o[(size_t)i * 8 + 4] = make_ushort4(u[4], u[5], u[6], u[7]);
}

// ---------------------------------------------------------------------------
// NT bf16 MFMA GEMM (m97 structure), 128x128 tile, 4 waves, 4x4 fragments.
// MODE 0: C row=d, col=bl -> xz[((col>>11)*D2 + row)*LL + (col&2047)]
// MODE 1: C row=bl, col=m -> out[row*DM + col]
// ---------------------------------------------------------------------------
template<int K, int MODE>
__global__ __launch_bounds__(256) void mfma_nt_k(const ushort* __restrict__ A,
                                                 const ushort* __restrict__ Bm,
                                                 float* __restrict__ C) {
    __shared__ ushort Als[128][32];
    __shared__ ushort Bls[128][32];
    const int n0 = blockIdx.x * 128;
    const int m0 = blockIdx.y * 128;
    const int tid = threadIdx.x;
    const int w = tid >> 6, lane = tid & 63;
    const int wr = (w >> 1) * 64, wc = (w & 1) * 64;
    const int lrow = lane & 15;
    const int kq = lane >> 4;

    const int srow = (lane >> 2);
    const int skof = (lane & 3) * 8;

    f32x4 acc[4][4] = {};
    for (int k0 = 0; k0 < K; k0 += 32) {
        #pragma unroll
        for (int j = 0; j < 2; j++) {
            const int rbase = w * 32 + j * 16;
            gload16(&A [(size_t)(m0 + rbase + srow) * K + k0 + skof], &Als[rbase][0]);
            gload16(&Bm[(size_t)(n0 + rbase + srow) * K + k0 + skof], &Bls[rbase][0]);
        }
        __syncthreads();
        short8v af[4], bf[4];
        #pragma unroll
        for (int i = 0; i < 4; i++) {
            af[i] = *(const short8v*)&Als[wr + i * 16 + lrow][kq * 8];
            bf[i] = *(const short8v*)&Bls[wc + i * 16 + lrow][kq * 8];
        }
        #pragma unroll
        for (int i = 0; i < 4; i++)
            #pragma unroll
            for (int jn = 0; jn < 4; jn++)
                acc[i][jn] = __builtin_amdgcn_mfma_f32_16x16x32_bf16(af[i], bf[jn], acc[i][jn], 0, 0, 0);
        __syncthreads();
    }
    #pragma unroll
    for (int i = 0; i < 4; i++) {
        #pragma unroll
        for (int jn = 0; jn < 4; jn++) {
            #pragma unroll
            for (int r = 0; r < 4; r++) {
                int row = m0 + wr + i * 16 + (lane >> 4) * 4 + r;
                int col = n0 + wc + jn * 16 + (lane & 15);
                size_t off;
                if constexpr (MODE == 0)
                    off = ((size_t)(col >> 11) * D2 + row) * LL + (col & (LL - 1));
                else
                    off = (size_t)row * DM + col;
                C[off] = acc[i][jn][r];
            }
        }
    }
}

// ---------------------------------------------------------------------------
// Depthwise causal conv(4) + bias + SiLU on x-half of xz -> xc
// ---------------------------------------------------------------------------
__global__ __launch_bounds__(256) void conv_silu_k(const float* __restrict__ xz,
                                                   const float* __restrict__ cw,
                                                   const float* __restrict__ cb,
                                                   float* __restrict__ xc) {
    const int row = blockIdx.x;             // 0..B*DI-1
    const int b = row / DI, d = row % DI;
    const float* xr = xz + ((size_t)b * D2 + d) * LL;
    float w0 = cw[d * 4 + 0], w1 = cw[d * 4 + 1];
    float w2 = cw[d * 4 + 2], w3 = cw[d * 4 + 3];
    float bias = cb[d];
    const int l0 = threadIdx.x * 8;
    float buf[11];
    #pragma unroll
    for (int i = 0; i < 11; i++) {
        int l = l0 - 3 + i;
        buf[i] = (l >= 0) ? xr[l] : 0.f;
    }
    float* out = xc + ((size_t)b * DI + d) * LL;
    #pragma unroll
    for (int j = 0; j < 8; j++) {
        float s = fmaf(buf[j], w0, fmaf(buf[j + 1], w1,
                  fmaf(buf[j + 2], w2, fmaf(buf[j + 3], w3, bias))));
        out[l0 + j] = s / (1.f + expf(-s));
    }
}

// ---------------------------------------------------------------------------
// x_dbl partials: part[seg][b][k][l] = sum_{d in seg} xc[b][d][l]*Wx[k][d]
// ---------------------------------------------------------------------------
__global__ __launch_bounds__(256) void xproj_partial_k(const float* __restrict__ xc,
                                                       const float* __restrict__ Wx,
                                                       float* __restrict__ part) {
    const int blk = blockIdx.x;            // b*64 + seg*8 + lt
    const int b = blk >> 6, seg = (blk >> 3) & 7, lt = blk & 7;
    const int l = lt * 256 + threadIdx.x;
    __shared__ float w[KX][64];
    float acc[KX] = {};
    const float* xb = xc + (size_t)b * DI * LL;
    for (int dc = 0; dc < 256; dc += 64) {
        const int dbase = seg * 256 + dc;
        __syncthreads();
        for (int i = threadIdx.x; i < KX * 64; i += 256) {
            int kk = i >> 6, dd = i & 63;
            w[kk][dd] = Wx[(size_t)kk * DI + dbase + dd];
        }
        __syncthreads();
        for (int dd = 0; dd < 64; dd++) {
            float v = xb[(size_t)(dbase + dd) * LL + l];
            #pragma unroll
            for (int kk = 0; kk < KX; kk++) acc[kk] = fmaf(v, w[kk][dd], acc[kk]);
        }
    }
    for (int kk = 0; kk < KX; kk++)
        part[(((size_t)seg * BB + b) * KX + kk) * LL + l] = acc[kk];
}

__global__ __launch_bounds__(256) void xproj_reduce_k(const float* __restrict__ part,
                                                      float* __restrict__ xdbl) {
    const int i = blockIdx.x * 256 + threadIdx.x;   // B*KX*L = 135168
    float s = 0.f;
    #pragma unroll
    for (int seg = 0; seg < 8; seg++) s += part[(size_t)seg * BB * KX * LL + i];
    xdbl[i] = s;
}

// ---------------------------------------------------------------------------
// Prep: dt = softplus(Wdt*dtr + bdt) -> xz z-half; zs = silu(z) -> xz x-half
// ---------------------------------------------------------------------------
__global__ __launch_bounds__(256) void prep_k(float* xz,
                                              const float* __restrict__ xdbl,
                                              const float* __restrict__ Wdt,
                                              const float* __restrict__ bdt) {
    const int row = blockIdx.x;              // b*DI + d
    const int b = row >> 11, d = row & (DI - 1);
    const float wdt = Wdt[d], bv = bdt[d];
    const float* dtr = xdbl + (size_t)b * KX * LL;         // row 0 = dt_raw
    float* zrow  = xz + ((size_t)b * D2 + DI + d) * LL;    // z in, dt out
    float* zsrow = xz + ((size_t)b * D2 + d) * LL;         // zs out
    const int l0 = threadIdx.x * 8;

    float4 dv0 = *(const float4*)&dtr[l0];
    float4 dv1 = *(const float4*)&dtr[l0 + 4];
    float4 zv0 = *(const float4*)&zrow[l0];
    float4 zv1 = *(const float4*)&zrow[l0 + 4];
    float dvv[8] = {dv0.x, dv0.y, dv0.z, dv0.w, dv1.x, dv1.y, dv1.z, dv1.w};
    float zvv[8] = {zv0.x, zv0.y, zv0.z, zv0.w, zv1.x, zv1.y, zv1.z, zv1.w};
    float dto[8], zso[8];
    #pragma unroll
    for (int k = 0; k < 8; k++) {
        float v = fmaf(wdt, dvv[k], bv);
        dto[k] = fmaxf(v, 0.f) + log1pf(expf(-fabsf(v)));   // stable softplus
        float z = zvv[k];
        zso[k] = z / (1.f + expf(-z));
    }
    *(float4*)&zrow[l0]      = make_float4(dto[0], dto[1], dto[2], dto[3]);
    *(float4*)&zrow[l0 + 4]  = make_float4(dto[4], dto[5], dto[6], dto[7]);
    *(float4*)&zsrow[l0]     = make_float4(zso[0], zso[1], zso[2], zso[3]);
    *(float4*)&zsrow[l0 + 4] = make_float4(zso[4], zso[5], zso[6], zso[7]);
}

// ---------------------------------------------------------------------------
// Local scan, thread-per-d, all 16 states in registers. h_in = 0.
// Writes: y0 (+x*Dskip) in-place over xc; cum (cumsum dt) in-place over dt;
// terminal h -> hloc. No cross-lane ops.
// ---------------------------------------------------------------------------
__global__ __launch_bounds__(256) void scan_local_k(float* xz,     // dt in / cum out (aliased, no restrict)
                                                    float* xc,     // x in / y0 out (own rows)
                                                    const float* __restrict__ xdbl,
                                                    const float* __restrict__ Alog,
                                                    const float* __restrict__ Dskip,
                                                    float* __restrict__ hloc) {
    const int blk = blockIdx.x;               // ((c*BB)+b)*8 + dblk
    const int dblk = blk & 7;
    const int b = (blk >> 3) & 1;
    const int c = blk >> 4;
    const int tid = threadIdx.x;
    const int d = dblk * 256 + tid;

    __shared__ float Bt[16][16];   // [t][n] — inner reads are wave-uniform (broadcast)
    __shared__ float Ct[16][16];

    float a2[16], h[16];
    #pragma unroll
    for (int n = 0; n < 16; n++) {
        a2[n] = -expf(Alog[(size_t)d * DS + n]) * 1.44269504f;
        h[n] = 0.f;
    }
    const float dsk = Dskip[d];
    float cum = 0.f;
    float* dtrow = xz + ((size_t)b * D2 + DI + d) * LL + c * LC;
    float* xrow  = xc + ((size_t)b * DI + d) * LL + c * LC;
    const float* Brow = xdbl + ((size_t)b * KX + 1) * LL + c * LC;
    const float* Crow = xdbl + ((size_t)b * KX + 17) * LL + c * LC;
    const int sn = tid >> 4, st = tid & 15;

    for (int c0 = 0; c0 < LC; c0 += 16) {
        float4 t0 = *(const float4*)&dtrow[c0 + 0];
        float4 t1 = *(const float4*)&dtrow[c0 + 4];
        float4 t2 = *(const float4*)&dtrow[c0 + 8];
        float4 t3 = *(const float4*)&dtrow[c0 + 12];
        float4 x0 = *(const float4*)&xrow[c0 + 0];
        float4 x1 = *(const float4*)&xrow[c0 + 4];
        float4 x2 = *(const float4*)&xrow[c0 + 8];
        float4 x3 = *(const float4*)&xrow[c0 + 12];
        float dreg[16] = {t0.x,t0.y,t0.z,t0.w, t1.x,t1.y,t1.z,t1.w,
                          t2.x,t2.y,t2.z,t2.w, t3.x,t3.y,t3.z,t3.w};
        float xreg[16] = {x0.x,x0.y,x0.z,x0.w, x1.x,x1.y,x1.z,x1.w,
                          x2.x,x2.y,x2.z,x2.w, x3.x,x3.y,x3.z,x3.w};
        __syncthreads();           // all readers of previous Bt/Ct done
        Bt[st][sn] = Brow[(size_t)sn * LL + c0 + st];
        Ct[st][sn] = Crow[(size_t)sn * LL + c0 + st];
        __syncthreads();

        float cw[16];
        #pragma unroll
        for (int j = 0; j < 16; j++) {
            float dt = dreg[j];
            cum += dt; cw[j] = cum;
            float u = dt * xreg[j];
            float4 b0 = *(const float4*)&Bt[j][0];
            float4 b1 = *(const float4*)&Bt[j][4];
            float4 b2 = *(const float4*)&Bt[j][8];
            float4 b3 = *(const float4*)&Bt[j][12];
            float4 q0 = *(const float4*)&Ct[j][0];
            float4 q1 = *(const float4*)&Ct[j][4];
            float4 q2 = *(const float4*)&Ct[j][8];
            float4 q3 = *(const float4*)&Ct[j][12];
            float bv[16] = {b0.x,b0.y,b0.z,b0.w, b1.x,b1.y,b1.z,b1.w,
                            b2.x,b2.y,b2.z,b2.w, b3.x,b3.y,b3.z,b3.w};
            float cv[16] = {q0.x,q0.y,q0.z,q0.w, q1.x,q1.y,q1.z,q1.w,
                            q2.x,q2.y,q2.z,q2.w, q3.x,q3.y,q3.z,q3.w};
            float y = 0.f;
            #pragma unroll
            for (int n = 0; n < 16; n++) {
                h[n] = fmaf(exp2f(a2[n] * dt), h[n], u * bv[n]);
                y = fmaf(h[n], cv[n], y);
            }
            xreg[j] = fmaf(xreg[j], dsk, y);   // y0 (+x*Dskip) overwrites x slot
        }
        *(float4*)&dtrow[c0 + 0]  = make_float4(cw[0],  cw[1],  cw[2],  cw[3]);
        *(float4*)&dtrow[c0 + 4]  = make_float4(cw[4],  cw[5],  cw[6],  cw[7]);
        *(float4*)&dtrow[c0 + 8]  = make_float4(cw[8],  cw[9],  cw[10], cw[11]);
        *(float4*)&dtrow[c0 + 12] = make_float4(cw[12], cw[13], cw[14], cw[15]);
        *(float4*)&xrow[c0 + 0]   = make_float4(xreg[0],  xreg[1],  xreg[2],  xreg[3]);
        *(float4*)&xrow[c0 + 4]   = make_float4(xreg[4],  xreg[5],  xreg[6],  xreg[7]);
        *(float4*)&xrow[c0 + 8]   = make_float4(xreg[8],  xreg[9],  xreg[10], xreg[11]);
        *(float4*)&xrow[c0 + 12]  = make_float4(xreg[12], xreg[13], xreg[14], xreg[15]);
    }
    float* hp = &hloc[(((size_t)c * BB + b) * DI + d) * DS];
    *(float4*)&hp[0]  = make_float4(h[0],  h[1],  h[2],  h[3]);
    *(float4*)&hp[4]  = make_float4(h[4],  h[5],  h[6],  h[7]);
    *(float4*)&hp[8]  = make_float4(h[8],  h[9],  h[10], h[11]);
    *(float4*)&hp[12] = make_float4(h[12], h[13], h[14], h[15]);
}

// ---------------------------------------------------------------------------
// Combine: serial over 32 chunk boundaries; chunk decay from cum endpoint.
// ---------------------------------------------------------------------------
__global__ __launch_bounds__(256) void combine2_k(const float* __restrict__ hloc,
                                                  const float* __restrict__ xz,  // cum (z-half)
                                                  const float* __restrict__ Alog,
                                                  float* __restrict__ hin) {
    const int i = blockIdx.x * 256 + threadIdx.x;   // (b*DI+d)*16+n
    const int n = i & 15;
    const int bd = i >> 4;
    const int d = bd & (DI - 1), b = bd >> 11;
    const float a2 = -expf(Alog[(size_t)d * DS + n]) * 1.44269504f;
    const float* crow = xz + ((size_t)b * D2 + DI + d) * LL;
    float h = 0.f;
    for (int c = 0; c < NC; c++) {
        size_t idx = ((size_t)c * BB * DI + bd) * DS + n;
        hin[idx] = h;
        float ce = crow[c * LC + LC - 1];
        h = fmaf(exp2f(a2 * ce), h, hloc[idx]);
    }
}

// ---------------------------------------------------------------------------
// y fixup (fully parallel): y = (y0 + sum_n C[n,l]*exp2(a2*cum[l])*hin[n])*zs,
// emitted as transposed bf16 ybf[(b*L+l)][d].
// ---------------------------------------------------------------------------
__global__ __launch_bounds__(256) void yfix_k(const float* __restrict__ xz,   // cum z-half, zs x-half
                                              const float* __restrict__ xc,   // y0
                                              const float* __restrict__ xdbl,
                                              const float* __restrict__ Alog,
                                              const float* __restrict__ hin,
                                              ushort* __restrict__ ybf) {
    const int bl0 = blockIdx.x * 64;
    const int b = bl0 >> 11, l0 = bl0 & (LL - 1);
    const int d0 = blockIdx.y * 64;
    const int c = l0 / LC;                    // chunk of this l-tile (LC==64)
    const int tid = threadIdx.x;
    const int dl = tid & 63;
    const int lq = tid >> 6;                  // 0..3 -> 16 l's each
    const int d = d0 + dl;

    __shared__ float Ctile[64][16];           // [l][n]
    __shared__ ushort sy[64][72];             // bf16 transpose tile (padded)

    {   // stage C
        int li = tid & 63, n4 = (tid >> 6) * 4;
        #pragma unroll
        for (int k = 0; k < 4; k++)
            Ctile[li][n4 + k] = xdbl[((size_t)b * KX + 17 + n4 + k) * LL + l0 + li];
    }
    float a2[16], hi[16];
    #pragma unroll
    for (int n = 0; n < 16; n++)
        a2[n] = -expf(Alog[(size_t)d * DS + n]) * 1.44269504f;
    {
        const float* hp = &hin[(((size_t)c * BB + b) * DI + d) * DS];
        float4 h0 = *(const float4*)&hp[0];
        float4 h1 = *(const float4*)&hp[4];
        float4 h2 = *(const float4*)&hp[8];
        float4 h3 = *(const float4*)&hp[12];
        float ht[16] = {h0.x,h0.y,h0.z,h0.w, h1.x,h1.y,h1.z,h1.w,
                        h2.x,h2.y,h2.z,h2.w, h3.x,h3.y,h3.z,h3.w};
        #pragma unroll
        for (int n = 0; n < 16; n++) hi[n] = ht[n];
    }
    const int lbase = l0 + lq * 16;
    const float* cumr = xz + ((size_t)b * D2 + DI + d) * LL + lbase;
    const float* y0r  = xc + ((size_t)b * DI + d) * LL + lbase;
    const float* zsr  = xz + ((size_t)b * D2 + d) * LL + lbase;
    float4 c0v = *(const float4*)&cumr[0], c1v = *(const float4*)&cumr[4];
    float4 c2v = *(const float4*)&cumr[8], c3v = *(const float4*)&cumr[12];
    float4 y0v = *(const float4*)&y0r[0],  y1v = *(const float4*)&y0r[4];
    float4 y2v = *(const float4*)&y0r[8],  y3v = *(const float4*)&y0r[12];
    float4 z0v = *(const float4*)&zsr[0],  z1v = *(const float4*)&zsr[4];
    float4 z2v = *(const float4*)&zsr[8],  z3v = *(const float4*)&zsr[12];
    float cm[16] = {c0v.x,c0v.y,c0v.z,c0v.w, c1v.x,c1v.y,c1v.z,c1v.w,
                    c2v.x,c2v.y,c2v.z,c2v.w, c3v.x,c3v.y,c3v.z,c3v.w};
    float yv[16] = {y0v.x,y0v.y,y0v.z,y0v.w, y1v.x,y1v.y,y1v.z,y1v.w,
                    y2v.x,y2v.y,y2v.z,y2v.w, y3v.x,y3v.y,y3v.z,y3v.w};
    float zv[16] = {z0v.x,z0v.y,z0v.z,z0v.w, z1v.x,z1v.y,z1v.z,z1v.w,
                    z2v.x,z2v.y,z2v.z,z2v.w, z3v.x,z3v.y,z3v.z,z3v.w};
    __syncthreads();
    #pragma unroll
    for (int j = 0; j < 16; j++) {
        int lidx = lq * 16 + j;
        float4 a0 = *(const float4*)&Ctile[lidx][0];
        float4 a1 = *(const float4*)&Ctile[lidx][4];
        float4 a2v = *(const float4*)&Ctile[lidx][8];
        float4 a3 = *(const float4*)&Ctile[lidx][12];
        float cv[16] = {a0.x,a0.y,a0.z,a0.w, a1.x,a1.y,a1.z,a1.w,
                        a2v.x,a2v.y,a2v.z,a2v.w, a3.x,a3.y,a3.z,a3.w};
        float corr = 0.f;
        #pragma unroll
        for (int n = 0; n < 16; n++)
            corr = fmaf(cv[n] * hi[n], exp2f(a2[n] * cm[j]), corr);
        float y = (yv[j] + corr) * zv[j];
        sy[lidx][dl] = tobf(y);
    }
    __syncthreads();
    {
        int lw = tid >> 2, p = tid & 3;
        uint4 v0 = *(const uint4*)&sy[lw][p * 16];
        uint4 v1 = *(const uint4*)&sy[lw][p * 16 + 8];
        ushort* orow = &ybf[((size_t)b * LL + l0 + lw) * DI + d0 + p * 16];
        *(uint4*)&orow[0] = v0;
        *(uint4*)&orow[8] = v1;
    }
}

// ---------------------------------------------------------------------------
extern "C" void kernel_launch(void* const* d_in, const int* in_sizes, int n_in,
                              void* d_out, int out_size, void* d_ws, size_t ws_size,
                              hipStream_t stream) {
    const float* hs   = (const float*)d_in[0];
    const float* Win  = (const float*)d_in[1];
    const float* cw   = (const float*)d_in[2];
    const float* cb   = (const float*)d_in[3];
    const float* Wx   = (const float*)d_in[4];
    const float* Wdt  = (const float*)d_in[5];
    const float* bdt  = (const float*)d_in[6];
    const float* Alog = (const float*)d_in[7];
    const float* Dsk  = (const float*)d_in[8];
    const float* Wout = (const float*)d_in[9];
    float* out = (float*)d_out;

    // layout (floats): total 31,592,448 = 126.4 MB (<= known-good 126.8)
    float* xz    = (float*)d_ws;                           // 16,777,216
    float* xc    = xz    + (size_t)BB * D2 * LL;           //  8,388,608
    float* xdbl  = xc    + (size_t)BB * DI * LL;           //    135,168
    float* part  = xdbl  + (size_t)BB * KX * LL;           //  2,097,152 slot
    float* hin   = part;                                   //  aliases part (dead after reduce)
    float* convf = part  + (size_t)NC * BB * DI * DS;      //  4,194,304 (Winb|hsb)

    ushort* Winb  = (ushort*)convf;                        // 4,194,304 u16
    ushort* hsb   = Winb + (size_t)D2 * DM;                // 4,194,304 u16
    float*  hloc  = (float*)hsb;                           // 2,097,152 f, aliases hsb (dead after gemm1)
    ushort* ybf   = (ushort*)convf;                        // aliases Winb+hsb (dead after combine/gemm1)
    ushort* Woutb = (ushort*)hin;                          // written after yfix (hin dead)

    cvt_bf16_k<<<2048, 256, 0, stream>>>(Win, Winb, (D2 * DM) / 8);
    cvt_bf16_k<<<2048, 256, 0, stream>>>(hs, hsb, (BB * LL * DM) / 8);
    mfma_nt_k<DM, 0><<<dim3(32, 32), 256, 0, stream>>>(Winb, hsb, xz);
    conv_silu_k<<<BB * DI, 256, 0, stream>>>(xz, cw, cb, xc);
    xproj_partial_k<<<128, 256, 0, stream>>>(xc, Wx, part);
    xproj_reduce_k<<<(BB * KX * LL) / 256, 256, 0, stream>>>(part, xdbl);
    prep_k<<<BB * DI, 256, 0, stream>>>(xz, xdbl, Wdt, bdt);
    scan_local_k<<<NC * BB * 8, 256, 0, stream>>>(xz, xc, xdbl, Alog, Dsk, hloc);
    combine2_k<<<(BB * DI * DS) / 256, 256, 0, stream>>>(hloc, xz, Alog, hin);
    yfix_k<<<dim3((BB * LL) / 64, DI / 64), 256, 0, stream>>>(xz, xc, xdbl, Alog, hin, ybf);
    cvt_bf16_k<<<1024, 256, 0, stream>>>(Wout, Woutb, (DM * DI) / 8);
    mfma_nt_k<DI, 1><<<dim3(8, 32), 256, 0, stream>>>(ybf, Woutb, out);
}

// Round 5
// 303.108 us; speedup vs baseline: 6.5955x; 1.2722x over previous
//
#include <hip/hip_runtime.h>
#include <hip/hip_bf16.h>
#include <math.h>

#define BB 2
#define LL 2048
#define DM 1024
#define DS 16
#define DI 2048
#define KX 33          // 1 + 2*D_STATE
#define D2 (2*DI)      // 4096
#define NC 32          // scan chunks
#define LC 64          // chunk length (NC*LC == LL)
#define SEGS 32        // xproj d-segments
#define SEGW 64        // d per segment

typedef __attribute__((ext_vector_type(8))) short short8v;   // 8 bf16 (4 VGPRs)
typedef __attribute__((ext_vector_type(4))) float f32x4;

__device__ __forceinline__ void gload16(const void* g, void* l) {
    __builtin_amdgcn_global_load_lds((const __attribute__((address_space(1))) void*)g,
                                     (__attribute__((address_space(3))) void*)l,
                                     16, 0, 0);
}

__device__ __forceinline__ ushort tobf(float v) {
    __hip_bfloat16 h = __float2bfloat16(v);
    return *(ushort*)&h;
}

// ---------------------------------------------------------------------------
// fp32 -> bf16 (RNE) conversion, 8 elems/thread
// ---------------------------------------------------------------------------
__global__ __launch_bounds__(256) void cvt_bf16_k(const float* __restrict__ in,
                                                  ushort* __restrict__ o, int n8) {
    int i = blockIdx.x * 256 + threadIdx.x;
    if (i >= n8) return;
    float4 a = *(const float4*)&in[(size_t)i * 8];
    float4 b = *(const float4*)&in[(size_t)i * 8 + 4];
    float v[8] = {a.x, a.y, a.z, a.w, b.x, b.y, b.z, b.w};
    ushort u[8];
    #pragma unroll
    for (int j = 0; j < 8; j++) u[j] = tobf(v[j]);
    *(ushort4*)&o[(size_t)i * 8]     = make_ushort4(u[0], u[1], u[2], u[3]);
    *(ushort4*)&o[(size_t)i * 8 + 4] = make_ushort4(u[4], u[5], u[6], u[7]);
}

// ---------------------------------------------------------------------------
// NT bf16 MFMA GEMM (m97 structure), 128x128 tile, 4 waves, 4x4 fragments.
// MODE 0: C row=d, col=bl -> xz[((col>>11)*D2 + row)*LL + (col&2047)]
// MODE 1: C row=bl, col=m -> out[row*DM + col]
// ---------------------------------------------------------------------------
template<int K, int MODE>
__global__ __launch_bounds__(256) void mfma_nt_k(const ushort* __restrict__ A,
                                                 const ushort* __restrict__ Bm,
                                                 float* __restrict__ C) {
    __shared__ ushort Als[128][32];
    __shared__ ushort Bls[128][32];
    const int n0 = blockIdx.x * 128;
    const int m0 = blockIdx.y * 128;
    const int tid = threadIdx.x;
    const int w = tid >> 6, lane = tid & 63;
    const int wr = (w >> 1) * 64, wc = (w & 1) * 64;
    const int lrow = lane & 15;
    const int kq = lane >> 4;

    const int srow = (lane >> 2);
    const int skof = (lane & 3) * 8;

    f32x4 acc[4][4] = {};
    for (int k0 = 0; k0 < K; k0 += 32) {
        #pragma unroll
        for (int j = 0; j < 2; j++) {
            const int rbase = w * 32 + j * 16;
            gload16(&A [(size_t)(m0 + rbase + srow) * K + k0 + skof], &Als[rbase][0]);
            gload16(&Bm[(size_t)(n0 + rbase + srow) * K + k0 + skof], &Bls[rbase][0]);
        }
        __syncthreads();
        short8v af[4], bf[4];
        #pragma unroll
        for (int i = 0; i < 4; i++) {
            af[i] = *(const short8v*)&Als[wr + i * 16 + lrow][kq * 8];
            bf[i] = *(const short8v*)&Bls[wc + i * 16 + lrow][kq * 8];
        }
        #pragma unroll
        for (int i = 0; i < 4; i++)
            #pragma unroll
            for (int jn = 0; jn < 4; jn++)
                acc[i][jn] = __builtin_amdgcn_mfma_f32_16x16x32_bf16(af[i], bf[jn], acc[i][jn], 0, 0, 0);
        __syncthreads();
    }
    #pragma unroll
    for (int i = 0; i < 4; i++) {
        #pragma unroll
        for (int jn = 0; jn < 4; jn++) {
            #pragma unroll
            for (int r = 0; r < 4; r++) {
                int row = m0 + wr + i * 16 + (lane >> 4) * 4 + r;
                int col = n0 + wc + jn * 16 + (lane & 15);
                size_t off;
                if constexpr (MODE == 0)
                    off = ((size_t)(col >> 11) * D2 + row) * LL + (col & (LL - 1));
                else
                    off = (size_t)row * DM + col;
                C[off] = acc[i][jn][r];
            }
        }
    }
}

// ---------------------------------------------------------------------------
// Depthwise causal conv(4) + bias + SiLU on x-half of xz -> xc
// ---------------------------------------------------------------------------
__global__ __launch_bounds__(256) void conv_silu_k(const float* __restrict__ xz,
                                                   const float* __restrict__ cw,
                                                   const float* __restrict__ cb,
                                                   float* __restrict__ xc) {
    const int row = blockIdx.x;             // 0..B*DI-1
    const int b = row / DI, d = row % DI;
    const float* xr = xz + ((size_t)b * D2 + d) * LL;
    float w0 = cw[d * 4 + 0], w1 = cw[d * 4 + 1];
    float w2 = cw[d * 4 + 2], w3 = cw[d * 4 + 3];
    float bias = cb[d];
    const int l0 = threadIdx.x * 8;
    float buf[11];
    #pragma unroll
    for (int i = 0; i < 11; i++) {
        int l = l0 - 3 + i;
        buf[i] = (l >= 0) ? xr[l] : 0.f;
    }
    float* out = xc + ((size_t)b * DI + d) * LL;
    #pragma unroll
    for (int j = 0; j < 8; j++) {
        float s = fmaf(buf[j], w0, fmaf(buf[j + 1], w1,
                  fmaf(buf[j + 2], w2, fmaf(buf[j + 3], w3, bias))));
        out[l0 + j] = s / (1.f + expf(-s));
    }
}

// ---------------------------------------------------------------------------
// x_dbl partials: part[seg][b][k][l] = sum_{d in seg(64)} xc[b][d][l]*Wx[k][d]
// grid = (8 l-tiles of 512) x (32 segs). Thread = 2 l's, 33 float2 accs.
// Weights LDS-broadcast as b128 reads; x loads float2 coalesced.
// ---------------------------------------------------------------------------
__global__ __launch_bounds__(256) void xproj_partial_k(const float* __restrict__ xc,
                                                       const float* __restrict__ Wx,
                                                       float* __restrict__ part) {
    const int lt = blockIdx.x;             // 0..7  (512 l each)
    const int seg = blockIdx.y;            // 0..31 (64 d each)
    const int tid = threadIdx.x;
    const int bl0 = lt * 512;
    const int b = bl0 >> 11;
    const int l = (bl0 & (LL - 1)) + tid * 2;
    const int dbase = seg * SEGW;

    __shared__ float w[SEGW][36];          // [dd][kk], row padded to 36 (16B-aligned)
    for (int kk = tid >> 6; kk < KX; kk += 4)
        w[tid & 63][kk] = Wx[(size_t)kk * DI + dbase + (tid & 63)];
    __syncthreads();

    float2 acc[KX];
    #pragma unroll
    for (int kk = 0; kk < KX; kk++) acc[kk] = make_float2(0.f, 0.f);

    const float* xb = xc + ((size_t)b * DI + dbase) * LL + l;
    #pragma unroll 4
    for (int dd = 0; dd < SEGW; dd++) {
        float2 xv = *(const float2*)&xb[(size_t)dd * LL];
        #pragma unroll
        for (int q = 0; q < 8; q++) {
            float4 wv = *(const float4*)&w[dd][q * 4];
            float wa[4] = {wv.x, wv.y, wv.z, wv.w};
            #pragma unroll
            for (int t = 0; t < 4; t++) {
                acc[q * 4 + t].x = fmaf(xv.x, wa[t], acc[q * 4 + t].x);
                acc[q * 4 + t].y = fmaf(xv.y, wa[t], acc[q * 4 + t].y);
            }
        }
        float wl = w[dd][32];
        acc[32].x = fmaf(xv.x, wl, acc[32].x);
        acc[32].y = fmaf(xv.y, wl, acc[32].y);
    }
    #pragma unroll
    for (int kk = 0; kk < KX; kk++)
        *(float2*)&part[(((size_t)seg * BB + b) * KX + kk) * LL + l] = acc[kk];
}

__global__ __launch_bounds__(256) void xproj_reduce_k(const float* __restrict__ part,
                                                      float* __restrict__ xdbl) {
    const int i = blockIdx.x * 256 + threadIdx.x;    // float4 index
    if (i >= (BB * KX * LL) / 4) return;
    float4 s = make_float4(0.f, 0.f, 0.f, 0.f);
    #pragma unroll
    for (int seg = 0; seg < SEGS; seg++) {
        float4 v = *(const float4*)&part[(size_t)seg * BB * KX * LL + (size_t)i * 4];
        s.x += v.x; s.y += v.y; s.z += v.z; s.w += v.w;
    }
    *(float4*)&xdbl[(size_t)i * 4] = s;
}

// ---------------------------------------------------------------------------
// Prep: dt = softplus(Wdt*dtr + bdt) -> xz z-half; zs = silu(z) -> xz x-half
// ---------------------------------------------------------------------------
__global__ __launch_bounds__(256) void prep_k(float* xz,
                                              const float* __restrict__ xdbl,
                                              const float* __restrict__ Wdt,
                                              const float* __restrict__ bdt) {
    const int row = blockIdx.x;              // b*DI + d
    const int b = row >> 11, d = row & (DI - 1);
    const float wdt = Wdt[d], bv = bdt[d];
    const float* dtr = xdbl + (size_t)b * KX * LL;         // row 0 = dt_raw
    float* zrow  = xz + ((size_t)b * D2 + DI + d) * LL;    // z in, dt out
    float* zsrow = xz + ((size_t)b * D2 + d) * LL;         // zs out
    const int l0 = threadIdx.x * 8;

    float4 dv0 = *(const float4*)&dtr[l0];
    float4 dv1 = *(const float4*)&dtr[l0 + 4];
    float4 zv0 = *(const float4*)&zrow[l0];
    float4 zv1 = *(const float4*)&zrow[l0 + 4];
    float dvv[8] = {dv0.x, dv0.y, dv0.z, dv0.w, dv1.x, dv1.y, dv1.z, dv1.w};
    float zvv[8] = {zv0.x, zv0.y, zv0.z, zv0.w, zv1.x, zv1.y, zv1.z, zv1.w};
    float dto[8], zso[8];
    #pragma unroll
    for (int k = 0; k < 8; k++) {
        float v = fmaf(wdt, dvv[k], bv);
        dto[k] = fmaxf(v, 0.f) + log1pf(expf(-fabsf(v)));   // stable softplus
        float z = zvv[k];
        zso[k] = z / (1.f + expf(-z));
    }
    *(float4*)&zrow[l0]      = make_float4(dto[0], dto[1], dto[2], dto[3]);
    *(float4*)&zrow[l0 + 4]  = make_float4(dto[4], dto[5], dto[6], dto[7]);
    *(float4*)&zsrow[l0]     = make_float4(zso[0], zso[1], zso[2], zso[3]);
    *(float4*)&zsrow[l0 + 4] = make_float4(zso[4], zso[5], zso[6], zso[7]);
}

// ---------------------------------------------------------------------------
// Local scan, thread-per-d, all 16 states in registers. h_in = 0.
// Writes: y0 (+x*Dskip) in-place over xc; cum (cumsum dt) in-place over dt;
// terminal h -> hloc. No cross-lane ops.
// ---------------------------------------------------------------------------
__global__ __launch_bounds__(256) void scan_local_k(float* xz,     // dt in / cum out (aliased, no restrict)
                                                    float* xc,     // x in / y0 out (own rows)
                                                    const float* __restrict__ xdbl,
                                                    const float* __restrict__ Alog,
                                                    const float* __restrict__ Dskip,
                                                    float* __restrict__ hloc) {
    const int blk = blockIdx.x;               // ((c*BB)+b)*8 + dblk
    const int dblk = blk & 7;
    const int b = (blk >> 3) & 1;
    const int c = blk >> 4;
    const int tid = threadIdx.x;
    const int d = dblk * 256 + tid;

    __shared__ float Bt[16][16];   // [t][n] — inner reads are wave-uniform (broadcast)
    __shared__ float Ct[16][16];

    float a2[16], h[16];
    #pragma unroll
    for (int n = 0; n < 16; n++) {
        a2[n] = -expf(Alog[(size_t)d * DS + n]) * 1.44269504f;
        h[n] = 0.f;
    }
    const float dsk = Dskip[d];
    float cum = 0.f;
    float* dtrow = xz + ((size_t)b * D2 + DI + d) * LL + c * LC;
    float* xrow  = xc + ((size_t)b * DI + d) * LL + c * LC;
    const float* Brow = xdbl + ((size_t)b * KX + 1) * LL + c * LC;
    const float* Crow = xdbl + ((size_t)b * KX + 17) * LL + c * LC;
    const int sn = tid >> 4, st = tid & 15;

    for (int c0 = 0; c0 < LC; c0 += 16) {
        float4 t0 = *(const float4*)&dtrow[c0 + 0];
        float4 t1 = *(const float4*)&dtrow[c0 + 4];
        float4 t2 = *(const float4*)&dtrow[c0 + 8];
        float4 t3 = *(const float4*)&dtrow[c0 + 12];
        float4 x0 = *(const float4*)&xrow[c0 + 0];
        float4 x1 = *(const float4*)&xrow[c0 + 4];
        float4 x2 = *(const float4*)&xrow[c0 + 8];
        float4 x3 = *(const float4*)&xrow[c0 + 12];
        float dreg[16] = {t0.x,t0.y,t0.z,t0.w, t1.x,t1.y,t1.z,t1.w,
                          t2.x,t2.y,t2.z,t2.w, t3.x,t3.y,t3.z,t3.w};
        float xreg[16] = {x0.x,x0.y,x0.z,x0.w, x1.x,x1.y,x1.z,x1.w,
                          x2.x,x2.y,x2.z,x2.w, x3.x,x3.y,x3.z,x3.w};
        __syncthreads();           // all readers of previous Bt/Ct done
        Bt[st][sn] = Brow[(size_t)sn * LL + c0 + st];
        Ct[st][sn] = Crow[(size_t)sn * LL + c0 + st];
        __syncthreads();

        float cw[16];
        #pragma unroll
        for (int j = 0; j < 16; j++) {
            float dt = dreg[j];
            cum += dt; cw[j] = cum;
            float u = dt * xreg[j];
            float4 b0 = *(const float4*)&Bt[j][0];
            float4 b1 = *(const float4*)&Bt[j][4];
            float4 b2 = *(const float4*)&Bt[j][8];
            float4 b3 = *(const float4*)&Bt[j][12];
            float4 q0 = *(const float4*)&Ct[j][0];
            float4 q1 = *(const float4*)&Ct[j][4];
            float4 q2 = *(const float4*)&Ct[j][8];
            float4 q3 = *(const float4*)&Ct[j][12];
            float bv[16] = {b0.x,b0.y,b0.z,b0.w, b1.x,b1.y,b1.z,b1.w,
                            b2.x,b2.y,b2.z,b2.w, b3.x,b3.y,b3.z,b3.w};
            float cv[16] = {q0.x,q0.y,q0.z,q0.w, q1.x,q1.y,q1.z,q1.w,
                            q2.x,q2.y,q2.z,q2.w, q3.x,q3.y,q3.z,q3.w};
            float y = 0.f;
            #pragma unroll
            for (int n = 0; n < 16; n++) {
                h[n] = fmaf(exp2f(a2[n] * dt), h[n], u * bv[n]);
                y = fmaf(h[n], cv[n], y);
            }
            xreg[j] = fmaf(xreg[j], dsk, y);   // y0 (+x*Dskip) overwrites x slot
        }
        *(float4*)&dtrow[c0 + 0]  = make_float4(cw[0],  cw[1],  cw[2],  cw[3]);
        *(float4*)&dtrow[c0 + 4]  = make_float4(cw[4],  cw[5],  cw[6],  cw[7]);
        *(float4*)&dtrow[c0 + 8]  = make_float4(cw[8],  cw[9],  cw[10], cw[11]);
        *(float4*)&dtrow[c0 + 12] = make_float4(cw[12], cw[13], cw[14], cw[15]);
        *(float4*)&xrow[c0 + 0]   = make_float4(xreg[0],  xreg[1],  xreg[2],  xreg[3]);
        *(float4*)&xrow[c0 + 4]   = make_float4(xreg[4],  xreg[5],  xreg[6],  xreg[7]);
        *(float4*)&xrow[c0 + 8]   = make_float4(xreg[8],  xreg[9],  xreg[10], xreg[11]);
        *(float4*)&xrow[c0 + 12]  = make_float4(xreg[12], xreg[13], xreg[14], xreg[15]);
    }
    float* hp = &hloc[(((size_t)c * BB + b) * DI + d) * DS];
    *(float4*)&hp[0]  = make_float4(h[0],  h[1],  h[2],  h[3]);
    *(float4*)&hp[4]  = make_float4(h[4],  h[5],  h[6],  h[7]);
    *(float4*)&hp[8]  = make_float4(h[8],  h[9],  h[10], h[11]);
    *(float4*)&hp[12] = make_float4(h[12], h[13], h[14], h[15]);
}

// ---------------------------------------------------------------------------
// Combine: serial over 32 chunk boundaries; chunk decay from cum endpoint.
// ---------------------------------------------------------------------------
__global__ __launch_bounds__(256) void combine2_k(const float* __restrict__ hloc,
                                                  const float* __restrict__ xz,  // cum (z-half)
                                                  const float* __restrict__ Alog,
                                                  float* __restrict__ hin) {
    const int i = blockIdx.x * 256 + threadIdx.x;   // (b*DI+d)*16+n
    const int n = i & 15;
    const int bd = i >> 4;
    const int d = bd & (DI - 1), b = bd >> 11;
    const float a2 = -expf(Alog[(size_t)d * DS + n]) * 1.44269504f;
    const float* crow = xz + ((size_t)b * D2 + DI + d) * LL;
    float h = 0.f;
    for (int c = 0; c < NC; c++) {
        size_t idx = ((size_t)c * BB * DI + bd) * DS + n;
        hin[idx] = h;
        float ce = crow[c * LC + LC - 1];
        h = fmaf(exp2f(a2 * ce), h, hloc[idx]);
    }
}

// ---------------------------------------------------------------------------
// y fixup (fully parallel): y = (y0 + sum_n C[n,l]*exp2(a2*cum[l])*hin[n])*zs,
// emitted as transposed bf16 ybf[(b*L+l)][d].
// ---------------------------------------------------------------------------
__global__ __launch_bounds__(256) void yfix_k(const float* __restrict__ xz,   // cum z-half, zs x-half
                                              const float* __restrict__ xc,   // y0
                                              const float* __restrict__ xdbl,
                                              const float* __restrict__ Alog,
                                              const float* __restrict__ hin,
                                              ushort* __restrict__ ybf) {
    const int bl0 = blockIdx.x * 64;
    const int b = bl0 >> 11, l0 = bl0 & (LL - 1);
    const int d0 = blockIdx.y * 64;
    const int c = l0 / LC;                    // chunk of this l-tile (LC==64)
    const int tid = threadIdx.x;
    const int dl = tid & 63;
    const int lq = tid >> 6;                  // 0..3 -> 16 l's each
    const int d = d0 + dl;

    __shared__ float Ctile[64][16];           // [l][n]
    __shared__ ushort sy[64][72];             // bf16 transpose tile (padded)

    {   // stage C
        int li = tid & 63, n4 = (tid >> 6) * 4;
        #pragma unroll
        for (int k = 0; k < 4; k++)
            Ctile[li][n4 + k] = xdbl[((size_t)b * KX + 17 + n4 + k) * LL + l0 + li];
    }
    float a2[16], hi[16];
    #pragma unroll
    for (int n = 0; n < 16; n++)
        a2[n] = -expf(Alog[(size_t)d * DS + n]) * 1.44269504f;
    {
        const float* hp = &hin[(((size_t)c * BB + b) * DI + d) * DS];
        float4 h0 = *(const float4*)&hp[0];
        float4 h1 = *(const float4*)&hp[4];
        float4 h2 = *(const float4*)&hp[8];
        float4 h3 = *(const float4*)&hp[12];
        float ht[16] = {h0.x,h0.y,h0.z,h0.w, h1.x,h1.y,h1.z,h1.w,
                        h2.x,h2.y,h2.z,h2.w, h3.x,h3.y,h3.z,h3.w};
        #pragma unroll
        for (int n = 0; n < 16; n++) hi[n] = ht[n];
    }
    const int lbase = l0 + lq * 16;
    const float* cumr = xz + ((size_t)b * D2 + DI + d) * LL + lbase;
    const float* y0r  = xc + ((size_t)b * DI + d) * LL + lbase;
    const float* zsr  = xz + ((size_t)b * D2 + d) * LL + lbase;
    float4 c0v = *(const float4*)&cumr[0], c1v = *(const float4*)&cumr[4];
    float4 c2v = *(const float4*)&cumr[8], c3v = *(const float4*)&cumr[12];
    float4 y0v = *(const float4*)&y0r[0],  y1v = *(const float4*)&y0r[4];
    float4 y2v = *(const float4*)&y0r[8],  y3v = *(const float4*)&y0r[12];
    float4 z0v = *(const float4*)&zsr[0],  z1v = *(const float4*)&zsr[4];
    float4 z2v = *(const float4*)&zsr[8],  z3v = *(const float4*)&zsr[12];
    float cm[16] = {c0v.x,c0v.y,c0v.z,c0v.w, c1v.x,c1v.y,c1v.z,c1v.w,
                    c2v.x,c2v.y,c2v.z,c2v.w, c3v.x,c3v.y,c3v.z,c3v.w};
    float yv[16] = {y0v.x,y0v.y,y0v.z,y0v.w, y1v.x,y1v.y,y1v.z,y1v.w,
                    y2v.x,y2v.y,y2v.z,y2v.w, y3v.x,y3v.y,y3v.z,y3v.w};
    float zv[16] = {z0v.x,z0v.y,z0v.z,z0v.w, z1v.x,z1v.y,z1v.z,z1v.w,
                    z2v.x,z2v.y,z2v.z,z2v.w, z3v.x,z3v.y,z3v.z,z3v.w};
    __syncthreads();
    #pragma unroll
    for (int j = 0; j < 16; j++) {
        int lidx = lq * 16 + j;
        float4 a0 = *(const float4*)&Ctile[lidx][0];
        float4 a1 = *(const float4*)&Ctile[lidx][4];
        float4 a2v = *(const float4*)&Ctile[lidx][8];
        float4 a3 = *(const float4*)&Ctile[lidx][12];
        float cv[16] = {a0.x,a0.y,a0.z,a0.w, a1.x,a1.y,a1.z,a1.w,
                        a2v.x,a2v.y,a2v.z,a2v.w, a3.x,a3.y,a3.z,a3.w};
        float corr = 0.f;
        #pragma unroll
        for (int n = 0; n < 16; n++)
            corr = fmaf(cv[n] * hi[n], exp2f(a2[n] * cm[j]), corr);
        float y = (yv[j] + corr) * zv[j];
        sy[lidx][dl] = tobf(y);
    }
    __syncthreads();
    {
        int lw = tid >> 2, p = tid & 3;
        uint4 v0 = *(const uint4*)&sy[lw][p * 16];
        uint4 v1 = *(const uint4*)&sy[lw][p * 16 + 8];
        ushort* orow = &ybf[((size_t)b * LL + l0 + lw) * DI + d0 + p * 16];
        *(uint4*)&orow[0] = v0;
        *(uint4*)&orow[8] = v1;
    }
}

// ---------------------------------------------------------------------------
extern "C" void kernel_launch(void* const* d_in, const int* in_sizes, int n_in,
                              void* d_out, int out_size, void* d_ws, size_t ws_size,
                              hipStream_t stream) {
    const float* hs   = (const float*)d_in[0];
    const float* Win  = (const float*)d_in[1];
    const float* cw   = (const float*)d_in[2];
    const float* cb   = (const float*)d_in[3];
    const float* Wx   = (const float*)d_in[4];
    const float* Wdt  = (const float*)d_in[5];
    const float* bdt  = (const float*)d_in[6];
    const float* Alog = (const float*)d_in[7];
    const float* Dsk  = (const float*)d_in[8];
    const float* Wout = (const float*)d_in[9];
    float* out = (float*)d_out;

    // layout (floats): total 31,592,448 = 126.4 MB (same as known-good R3/R4)
    float* xz    = (float*)d_ws;                           // 16,777,216
    float* xc    = xz    + (size_t)BB * D2 * LL;           //  8,388,608
    float* xdbl  = xc    + (size_t)BB * DI * LL;           //    135,168
    float* part  = xdbl  + (size_t)BB * KX * LL;           //  4,325,376 (spans hin-slot + Winb + head of hsb;
                                                           //   live only between gemm1 and xproj_reduce)
    float* hin   = part;                                   //  2,097,152 (combine2 -> yfix; part dead)
    float* convf = part  + (size_t)2097152;                //  4,194,304 f region (Winb|hsb / ybf)

    ushort* Winb  = (ushort*)convf;                        // 4,194,304 u16 (dead after gemm1)
    ushort* hsb   = Winb + (size_t)D2 * DM;                // 4,194,304 u16 (dead after gemm1)
    float*  hloc  = (float*)hsb;                           // 2,097,152 f (scan_local -> combine2)
    ushort* ybf   = (ushort*)convf;                        // written at yfix (all aliases dead)
    ushort* Woutb = (ushort*)hin;                          // written after yfix (hin dead)

    cvt_bf16_k<<<2048, 256, 0, stream>>>(Win, Winb, (D2 * DM) / 8);
    cvt_bf16_k<<<2048, 256, 0, stream>>>(hs, hsb, (BB * LL * DM) / 8);
    mfma_nt_k<DM, 0><<<dim3(32, 32), 256, 0, stream>>>(Winb, hsb, xz);
    conv_silu_k<<<BB * DI, 256, 0, stream>>>(xz, cw, cb, xc);
    xproj_partial_k<<<dim3(8, SEGS), 256, 0, stream>>>(xc, Wx, part);
    xproj_reduce_k<<<(BB * KX * LL / 4 + 255) / 256, 256, 0, stream>>>(part, xdbl);
    prep_k<<<BB * DI, 256, 0, stream>>>(xz, xdbl, Wdt, bdt);
    scan_local_k<<<NC * BB * 8, 256, 0, stream>>>(xz, xc, xdbl, Alog, Dsk, hloc);
    combine2_k<<<(BB * DI * DS) / 256, 256, 0, stream>>>(hloc, xz, Alog, hin);
    yfix_k<<<dim3((BB * LL) / 64, DI / 64), 256, 0, stream>>>(xz, xc, xdbl, Alog, hin, ybf);
    cvt_bf16_k<<<1024, 256, 0, stream>>>(Wout, Woutb, (DM * DI) / 8);
    mfma_nt_k<DI, 1><<<dim3(8, 32), 256, 0, stream>>>(ybf, Woutb, out);
}